// Round 7
// baseline (940.179 us; speedup 1.0000x reference)
//
#include <hip/hip_runtime.h>
#include <hip/hip_cooperative_groups.h>

namespace cg = cooperative_groups;

#define BR 64
#define EC 131072
#define BINS 4096
#define CAP 4096
#define LCAP 1024
#define CHUNKS 16
#define CHUNK_V (EC / CHUNKS / 4)   // float4 per chunk = 2048
#define GRID 1024

// ws word-offset layout
#define WS_GMAX 0
#define WS_ACTIVE 1
#define WS_TOACT 2
#define WS_B1 8        // +row
#define WS_KREM 72     // +row
#define WS_UT 136      // +row
#define WS_CUT 200     // +row
#define WS_CCNT 264    // +row
#define WS_UT2 512     // +row (correction branch)
#define WS_CUT2 576    // +row
#define HIST_OFF 1024
#define CAND_U_OFF (HIST_OFF + BR * BINS)
#define CAND_I_OFF (CAND_U_OFF + BR * CAP)
#define ZERO_WORDS CAND_U_OFF

__device__ __forceinline__ unsigned map_f(float f) {
    unsigned b = __float_as_uint(f);
    return (b & 0x80000000u) ? ~b : (b | 0x80000000u);
}
__device__ __forceinline__ float unmap_f(unsigned u) {
    unsigned b = (u & 0x80000000u) ? (u & 0x7FFFFFFFu) : ~u;
    return __uint_as_float(b);
}

// EXACT numpy-op-sequence value computation; contract(off) so every phase
// computes bit-identical values.
__device__ __forceinline__ void compute_vals(float x, float bt, float gmax, float bp,
                                             float* nb, float* bo) {
#pragma clang fp contract(off)
    float q = x / gmax;
    float t = 1.0f - q;
    float p = t * bp;
    float nbv = bt + p;
    *nb = nbv;
    *bo = fmaxf(x, 0.0f) + nbv;
}

__device__ __forceinline__ unsigned umax_(unsigned a, unsigned b) { return a > b ? a : b; }
__device__ __forceinline__ unsigned vload(volatile unsigned* p) { return *p; }

__global__ __launch_bounds__(256, 4) void fused(
        const float4* __restrict__ x4, const float4* __restrict__ bt4,
        const float* __restrict__ sp, const float* __restrict__ bp_p,
        unsigned* __restrict__ ws, float4* __restrict__ out4,
        float4* __restrict__ fb4) {
    cg::grid_group grid = cg::this_grid();
    __shared__ unsigned smem[2 * BINS];   // 32KB, aliased per phase
    const int t = threadIdx.x;
    const int bid = blockIdx.x;
    const int gsz = GRID * 256;
    const int gtid = bid * 256 + t;

    // ---------- P0: zero scratch header ----------
    for (int i = gtid; i < ZERO_WORDS; i += gsz) ws[i] = 0u;
    grid.sync();

    // ---------- P1: global max of x ----------
    {
        unsigned m = 0;
        const int nvec = BR * EC / 4;
        for (int v = gtid; v < nvec; v += gsz) {
            float4 xv = x4[v];
            m = umax_(m, map_f(xv.x)); m = umax_(m, map_f(xv.y));
            m = umax_(m, map_f(xv.z)); m = umax_(m, map_f(xv.w));
        }
        for (int off = 32; off; off >>= 1) m = umax_(m, __shfl_down(m, off, 64));
        if ((t & 63) == 0) smem[t >> 6] = m;
        __syncthreads();
        if (t == 0) {
            unsigned mm = umax_(umax_(smem[0], smem[1]), umax_(smem[2], smem[3]));
            atomicMax(&ws[WS_GMAX], mm);
        }
    }
    grid.sync();

    const float gmax = unmap_f(vload(&ws[WS_GMAX]));
    const float bp = *bp_p;
    const int row16 = bid >> 4, chunk = bid & (CHUNKS - 1);
    const size_t base16 = (size_t)row16 * (EC / 4) + (size_t)chunk * CHUNK_V;

    // ---------- P2: per-row 4096-bin histogram (2 LDS copies per block) ----------
    {
        for (int i = t; i < 2 * BINS; i += 256) smem[i] = 0;
        __syncthreads();
        unsigned* h = smem + (t >> 7) * BINS;
        for (int v = t; v < CHUNK_V; v += 256) {
            float4 xv = x4[base16 + v];
            float4 bv = bt4[base16 + v];
            float xs[4] = {xv.x, xv.y, xv.z, xv.w};
            float bs[4] = {bv.x, bv.y, bv.z, bv.w};
            #pragma unroll
            for (int j = 0; j < 4; ++j) {
                float nb, bo;
                compute_vals(xs[j], bs[j], gmax, bp, &nb, &bo);
                atomicAdd(&h[map_f(bo) >> 20], 1u);
            }
        }
        __syncthreads();
        unsigned* gh = ws + HIST_OFF + (size_t)row16 * BINS;
        int rot = chunk * 256;
        for (int i0 = t; i0 < BINS; i0 += 256) {
            int i = (i0 + rot) & (BINS - 1);
            unsigned v = smem[i] + smem[BINS + i];
            if (v) atomicAdd(&gh[i], v);
        }
    }
    grid.sync();

    // ---------- P3: find bin of K-th largest (blocks 0..63) ----------
    if (bid < BR) {
        int row = bid;
        unsigned K = (unsigned)ceilf(sp[1] * (float)EC);
        if (K > EC) K = EC;
        if (K == 0) K = 1;
        const unsigned* gh = ws + HIST_OFF + (size_t)row * BINS;
        unsigned* ssum = smem;
        unsigned* sabove = smem + 256;
        unsigned hv[16];
        unsigned s = 0;
        #pragma unroll
        for (int j = 0; j < 16; ++j) { hv[j] = gh[t * 16 + j]; s += hv[j]; }
        ssum[t] = s;
        __syncthreads();
        if (t == 0) {
            unsigned acc = 0;
            for (int q = 255; q >= 0; --q) { sabove[q] = acc; acc += ssum[q]; }
        }
        __syncthreads();
        unsigned cum = sabove[t];
        for (int j = 15; j >= 0; --j) {
            unsigned h = hv[j];
            if (cum < K && cum + h >= K) {
                ws[WS_B1 + row] = (unsigned)(t * 16 + j);
                ws[WS_KREM + row] = K - cum;
            }
            cum += h;
        }
    }
    grid.sync();

    // ---------- P4: collect candidates (block-aggregated reservation) ----------
    {
        unsigned* lu = smem;
        unsigned* li = smem + LCAP;
        if (t == 0) smem[2 * LCAP] = 0;
        __syncthreads();
        unsigned b1 = vload(&ws[WS_B1 + row16]);
        unsigned* cu = ws + CAND_U_OFF + (size_t)row16 * CAP;
        unsigned* ci = ws + CAND_I_OFF + (size_t)row16 * CAP;
        int ebase = chunk * (EC / CHUNKS);
        for (int v = t; v < CHUNK_V; v += 256) {
            float4 xv = x4[base16 + v];
            float4 bv = bt4[base16 + v];
            float xs[4] = {xv.x, xv.y, xv.z, xv.w};
            float bs[4] = {bv.x, bv.y, bv.z, bv.w};
            #pragma unroll
            for (int j = 0; j < 4; ++j) {
                float nb, bo;
                compute_vals(xs[j], bs[j], gmax, bp, &nb, &bo);
                unsigned u = map_f(bo);
                if ((u >> 20) == b1) {
                    unsigned p = atomicAdd(&smem[2 * LCAP], 1u);
                    if (p < LCAP) {
                        lu[p] = u; li[p] = (unsigned)(ebase + v * 4 + j);
                    } else {
                        unsigned gp = atomicAdd(&ws[WS_CCNT + row16], 1u);
                        if (gp < CAP) { cu[gp] = u; ci[gp] = (unsigned)(ebase + v * 4 + j); }
                    }
                }
            }
        }
        __syncthreads();
        unsigned n = smem[2 * LCAP];
        if (n > LCAP) n = LCAP;
        if (t == 0) smem[2 * LCAP + 1] = atomicAdd(&ws[WS_CCNT + row16], n);
        __syncthreads();
        unsigned gb = smem[2 * LCAP + 1];
        for (unsigned i = t; i < n; i += 256) {
            unsigned gp = gb + i;
            if (gp < CAP) { cu[gp] = lu[i]; ci[gp] = li[i]; }
        }
    }
    grid.sync();

    // ---------- P5: exact select + stable tie-cut (blocks 0..63) ----------
    if (bid < BR) {
        int row = bid;
        unsigned n = vload(&ws[WS_CCNT + row]);
        if (n > CAP) n = CAP;
        unsigned b1 = ws[WS_B1 + row];     // written by this same block in P3
        unsigned K = ws[WS_KREM + row];
        const unsigned* cu = ws + CAND_U_OFF + (size_t)row * CAP;
        const unsigned* ci = ws + CAND_I_OFF + (size_t)row * CAP;
        unsigned* su   = smem;             // 4096
        unsigned* hist = smem + 4096;      // 256
        unsigned* scan = smem + 4352;      // 256
        unsigned* sb   = smem + 4608;      // 2
        unsigned* marr = smem + 4612;      // 256 (mcnt at smem[4611])
        for (unsigned i = t; i < n; i += 256) su[i] = cu[i];
        if (t == 0) smem[4611] = 0;
        __syncthreads();

        unsigned pv = b1 << 20;
        unsigned Kp = K;
        const int shifts[3] = {12, 4, 0};
        const unsigned wmask[3] = {0xFFu, 0xFFu, 0xFu};
        const unsigned pmask[3] = {0xFFF00000u, 0xFFFFF000u, 0xFFFFFFF0u};
        for (int pass = 0; pass < 3; ++pass) {
            int shift = shifts[pass];
            unsigned msk = wmask[pass];
            hist[t] = 0;
            __syncthreads();
            for (unsigned i = t; i < n; i += 256) {
                unsigned u = su[i];
                if ((u & pmask[pass]) == pv) atomicAdd(&hist[(u >> shift) & msk], 1u);
            }
            __syncthreads();
            unsigned my = hist[t];
            scan[t] = my;
            __syncthreads();
            for (int off = 1; off < 256; off <<= 1) {
                unsigned v = (t + off < 256) ? scan[t + off] : 0u;
                __syncthreads();
                scan[t] += v;
                __syncthreads();
            }
            unsigned incl = scan[t], excl = incl - my;
            if ((unsigned)t <= msk && excl < Kp && incl >= Kp) {
                sb[0] = pv | ((unsigned)t << shift);
                sb[1] = Kp - excl;
            }
            __syncthreads();
            pv = sb[0];
            Kp = sb[1];
            __syncthreads();
        }
        unsigned u_t = pv, krem2 = Kp;

        for (unsigned i = t; i < n; i += 256)
            if (su[i] == u_t) {
                unsigned p = atomicAdd(&smem[4611], 1u);
                if (p < 256) marr[p] = ci[i];
            }
        __syncthreads();
        unsigned m = smem[4611];
        if (m <= 256) {
            for (unsigned i = t; i < m; i += 256) {
                unsigned myidx = marr[i];
                unsigned r = 0;
                for (unsigned j = 0; j < m; ++j) r += (marr[j] < myidx) ? 1u : 0u;
                if (r == krem2 - 1) { ws[WS_UT + row] = u_t; ws[WS_CUT + row] = myidx; }
            }
        } else {  // pathological tie overflow: correct slow path
            for (unsigned i = t; i < n; i += 256) {
                if (su[i] == u_t) {
                    unsigned myidx = ci[i];
                    unsigned r = 0;
                    for (unsigned j = 0; j < n; ++j)
                        if (su[j] == u_t && ci[j] < myidx) ++r;
                    if (r == krem2 - 1) { ws[WS_UT + row] = u_t; ws[WS_CUT + row] = myidx; }
                }
            }
        }
    }
    grid.sync();

    // ---------- P6: mark + write outputs + count active ----------
    {
        unsigned cnt = 0;
        const size_t nvec = (size_t)BR * EC / 4;
        for (size_t v = (size_t)gtid; v < nvec; v += gsz) {
            size_t e0 = v << 2;
            int row = (int)(e0 >> 17);
            int col = (int)(e0 & (size_t)(EC - 1));
            unsigned u_t = vload(&ws[WS_UT + row]);
            int cut = (int)vload(&ws[WS_CUT + row]);
            float4 xv = x4[v], bv = bt4[v];
            float xarr[4] = {xv.x, xv.y, xv.z, xv.w};
            float barr[4] = {bv.x, bv.y, bv.z, bv.w};
            float o[4], f[4];
            #pragma unroll
            for (int j = 0; j < 4; ++j) {
                float nb, bo;
                compute_vals(xarr[j], barr[j], gmax, bp, &nb, &bo);
                unsigned u = map_f(bo);
                bool sel = (u > u_t) || ((u == u_t) && ((col + j) <= cut));
                bool saved = sel && (u > 0x80000000u);   // boosted > 0
                o[j] = saved ? 1.0f : 0.0f;
                f[j] = saved ? 0.0f : nb;
                cnt += saved ? 1u : 0u;
            }
            out4[v] = make_float4(o[0], o[1], o[2], o[3]);
            fb4[v] = make_float4(f[0], f[1], f[2], f[3]);
        }
        for (int off = 32; off; off >>= 1) cnt += __shfl_down(cnt, off, 64);
        if (t == 0) smem[0] = 0;
        __syncthreads();
        if ((t & 63) == 0) atomicAdd(&smem[0], cnt);
        __syncthreads();
        if (t == 0) atomicAdd(&ws[WS_ACTIVE], smem[0]);
    }
    grid.sync();

    // ---------- P7: to_activate ----------
    if (bid == 0 && t == 0) {
        float min_active = floorf(sp[0] * (float)EC);
        float active = (float)vload(&ws[WS_ACTIVE]);
        ws[WS_TOACT] = (active < min_active) ? (unsigned)ceilf(min_active - active) : 0u;
    }
    grid.sync();

    unsigned toact = vload(&ws[WS_TOACT]);
    if (toact) {   // grid-uniform; dead for this input but faithful
        // ---------- P8: per-row select on new_boost (blocks 0..63) ----------
        if (bid < BR) {
            unsigned K = toact;
            if (K > EC) K = EC;
            int row = bid;
            const float4* xr4 = x4 + (size_t)row * (EC / 4);
            const float4* br4 = bt4 + (size_t)row * (EC / 4);
            unsigned* hist = smem;        // 256
            unsigned* sb = smem + 256;    // 2
            unsigned* wcnt = smem + 260;  // 4
            // smem[266]=run, smem[267]=cut
            unsigned prefix = 0, Kp = K;
            for (int pass = 0; pass < 4; ++pass) {
                const int shift = 24 - 8 * pass;
                hist[t] = 0;
                __syncthreads();
                for (int v = t; v < EC / 4; v += 256) {
                    float4 xv = xr4[v];
                    float4 bv = br4[v];
                    float xs[4] = {xv.x, xv.y, xv.z, xv.w};
                    float bs[4] = {bv.x, bv.y, bv.z, bv.w};
                    #pragma unroll
                    for (int j = 0; j < 4; ++j) {
                        float nb, bo;
                        compute_vals(xs[j], bs[j], gmax, bp, &nb, &bo);
                        unsigned u = map_f(nb);
                        bool match = (pass == 0) || ((u >> (32 - 8 * pass)) == prefix);
                        if (match) atomicAdd(&hist[(u >> shift) & 0xFFu], 1u);
                    }
                }
                __syncthreads();
                if (t == 0) {
                    unsigned cum = 0, bsel = 0, krem = Kp;
                    for (int b = 255; b >= 0; --b) {
                        unsigned h = hist[b];
                        if (cum + h >= Kp) { bsel = (unsigned)b; krem = Kp - cum; break; }
                        cum += h;
                    }
                    sb[0] = (prefix << 8) | bsel;
                    sb[1] = krem;
                }
                __syncthreads();
                prefix = sb[0];
                Kp = sb[1];
                __syncthreads();
            }
            unsigned u_t = prefix, ties = Kp;
            if (t == 0) { smem[266] = 0; smem[267] = 0xFFFFFFFFu; }
            __syncthreads();
            int wid = t >> 6, lane = t & 63;
            const float* xs = (const float*)xr4;
            const float* bs = (const float*)br4;
            for (int base0 = 0; base0 < EC; base0 += 256) {
                int i = base0 + t;
                bool eq = false;
                {
                    float nb, bo;
                    compute_vals(xs[i], bs[i], gmax, bp, &nb, &bo);
                    eq = (map_f(nb) == u_t);
                }
                unsigned long long bal = __ballot(eq);
                if (lane == 0) wcnt[wid] = (unsigned)__popcll(bal);
                __syncthreads();
                unsigned run = smem[266];
                unsigned wpre = 0;
                for (int w = 0; w < wid; ++w) wpre += wcnt[w];
                if (eq) {
                    unsigned r = run + wpre + (unsigned)__popcll(bal & ((1ull << lane) - 1ull));
                    if (r == ties - 1) smem[267] = (unsigned)i;
                }
                __syncthreads();
                if (t == 0) smem[266] = run + wcnt[0] + wcnt[1] + wcnt[2] + wcnt[3];
                __syncthreads();
                if (smem[266] >= ties) break;
            }
            if (t == 0) {
                ws[WS_UT2 + row] = u_t;
                ws[WS_CUT2 + row] = smem[267];
            }
        }
        grid.sync();

        // ---------- P9: apply correction ----------
        const size_t nvec = (size_t)BR * EC / 4;
        float* outp = (float*)out4;
        float* fbp = (float*)fb4;
        for (size_t v = (size_t)gtid; v < nvec; v += gsz) {
            size_t e0 = v << 2;
            int row = (int)(e0 >> 17);
            int col = (int)(e0 & (size_t)(EC - 1));
            unsigned u_t = vload(&ws[WS_UT2 + row]);
            int cut = (int)vload(&ws[WS_CUT2 + row]);
            float4 xv = x4[v], bv = bt4[v];
            float xarr[4] = {xv.x, xv.y, xv.z, xv.w};
            float barr[4] = {bv.x, bv.y, bv.z, bv.w};
            #pragma unroll
            for (int j = 0; j < 4; ++j) {
                float nb, bo;
                compute_vals(xarr[j], barr[j], gmax, bp, &nb, &bo);
                unsigned u = map_f(nb);
                if (u > u_t || (u == u_t && (col + j) <= cut)) {
                    outp[e0 + j] = 1.0f;
                    fbp[e0 + j] = 0.0f;
                }
            }
        }
    }
}

extern "C" void kernel_launch(void* const* d_in, const int* in_sizes, int n_in,
                              void* d_out, int out_size, void* d_ws, size_t ws_size,
                              hipStream_t stream) {
    const float4* x4 = (const float4*)d_in[0];
    const float4* bt4 = (const float4*)d_in[1];
    const float* sp = (const float*)d_in[2];
    const float* bp = (const float*)d_in[3];
    float4* out4 = (float4*)d_out;
    float4* fb4 = (float4*)((float*)d_out + (size_t)BR * EC);
    unsigned* ws = (unsigned*)d_ws;

    void* args[] = {(void*)&x4, (void*)&bt4, (void*)&sp, (void*)&bp,
                    (void*)&ws, (void*)&out4, (void*)&fb4};
    hipLaunchCooperativeKernel((const void*)fused, dim3(GRID), dim3(256),
                               args, 0, stream);
}

// Round 10
// 97.256 us; speedup vs baseline: 9.6671x; 9.6671x over previous
//
#include <hip/hip_runtime.h>

#define BR 64
#define EC 131072
#define CAP 8192
#define LCAP 1024
#define CHUNKS 16
#define CHUNK_V (EC / CHUNKS / 4)   // float4 per chunk = 2048
#define NSCH 41
#define NS (NSCH * 64)              // 2624 samples per row
#define SSTRIDE 3197                // 40*3197+63 = 127943 < EC

typedef float nf4 __attribute__((ext_vector_type(4)));   // native vec for nontemporal

// ws word-offset layout
#define WS_GMAX 0
#define WS_ACTIVE 1
#define WS_TOACT 2
#define WS_TLO 8       // +row
#define WS_UT 136      // +row
#define WS_CUT 200     // +row
#define WS_CCNT 264    // +row
#define WS_UT2 512     // +row (correction branch)
#define WS_CUT2 576    // +row
#define WS_BMAX 1024   // +1024 per-block maxima (written unconditionally)
#define CAND_U_OFF 4096
#define CAND_I_OFF (CAND_U_OFF + BR * CAP)

// Monotonic float->uint mapping (order-preserving, bijective)
__device__ __forceinline__ unsigned map_f(float f) {
    unsigned b = __float_as_uint(f);
    return (b & 0x80000000u) ? ~b : (b | 0x80000000u);
}
__device__ __forceinline__ float unmap_f(unsigned u) {
    unsigned b = (u & 0x80000000u) ? (u & 0x7FFFFFFFu) : ~u;
    return __uint_as_float(b);
}

// EXACT numpy-op-sequence value computation; contract(off) so every kernel
// computes bit-identical values.
__device__ __forceinline__ void compute_vals(float x, float bt, float gmax, float bp,
                                             float* nb, float* bo) {
#pragma clang fp contract(off)
    float q = x / gmax;
    float t = 1.0f - q;
    float p = t * bp;
    float nbv = bt + p;
    *nb = nbv;
    *bo = fmaxf(x, 0.0f) + nbv;
}

__device__ __forceinline__ unsigned umax_(unsigned a, unsigned b) { return a > b ? a : b; }

__device__ __forceinline__ unsigned calc_K(const float* sp) {
    unsigned K = (unsigned)ceilf(sp[1] * (float)EC);
    if (K > EC) K = EC;
    if (K == 0) K = 1;
    return K;
}

// Radix select (descending rank K) over n values in LDS array su.
// hist/scan: 256-word LDS scratch; sb: 2-word LDS. Returns u_t; *krem = rank within ties.
__device__ unsigned lds_radix_select(const unsigned* su, unsigned n, unsigned K,
                                     unsigned* hist, unsigned* scan, unsigned* sb,
                                     int t, unsigned* krem) {
    unsigned pv = 0, Kp = K;
    for (int pass = 0; pass < 4; ++pass) {
        int shift = 24 - 8 * pass;
        hist[t] = 0;
        __syncthreads();
        for (unsigned i = t; i < n; i += 256) {
            unsigned u = su[i];
            bool match = (pass == 0) || ((u >> (shift + 8)) == (pv >> (shift + 8)));
            if (match) atomicAdd(&hist[(u >> shift) & 0xFFu], 1u);
        }
        __syncthreads();
        unsigned my = hist[t];
        scan[t] = my;
        __syncthreads();
        for (int off = 1; off < 256; off <<= 1) {
            unsigned v = (t + off < 256) ? scan[t + off] : 0u;
            __syncthreads();
            scan[t] += v;
            __syncthreads();
        }
        unsigned incl = scan[t], excl = incl - my;
        if (excl < Kp && incl >= Kp) {
            sb[0] = pv | ((unsigned)t << shift);
            sb[1] = Kp - excl;
        }
        __syncthreads();
        pv = sb[0];
        Kp = sb[1];
        __syncthreads();
    }
    *krem = Kp;
    return pv;
}

// Exact full-row select on bo (use_nb=0) or nb (use_nb=1): 4-pass 256-bin radix over
// global data + ordered stable tie scan. 256 threads. hist: 256 LDS; aux: 8 LDS.
template<int USE_NB>
__device__ void row_select_full(const float* xr, const float* br, float gmax, float bp,
                                unsigned K, unsigned* hist, unsigned* aux, int t,
                                unsigned* ut_out, unsigned* cut_out) {
    unsigned prefix = 0, Kp = K;
    for (int pass = 0; pass < 4; ++pass) {
        int shift = 24 - 8 * pass;
        hist[t] = 0;
        __syncthreads();
        for (int i = t; i < EC; i += 256) {
            float nb, bo;
            compute_vals(xr[i], br[i], gmax, bp, &nb, &bo);
            unsigned u = map_f(USE_NB ? nb : bo);
            bool match = (pass == 0) || ((u >> (shift + 8)) == (prefix >> (shift + 8)));
            if (match) atomicAdd(&hist[(u >> shift) & 0xFFu], 1u);
        }
        __syncthreads();
        if (t == 0) {
            unsigned cum = 0, bsel = 0, kr = Kp;
            for (int b = 255; b >= 0; --b) {
                unsigned h = hist[b];
                if (cum + h >= Kp) { bsel = (unsigned)b; kr = Kp - cum; break; }
                cum += h;
            }
            aux[0] = prefix | (bsel << shift);
            aux[1] = kr;
        }
        __syncthreads();
        prefix = aux[0];
        Kp = aux[1];
        __syncthreads();
    }
    unsigned u_t = prefix, ties = Kp;
    if (t == 0) { aux[6] = 0; aux[7] = 0xFFFFFFFFu; }
    __syncthreads();
    int wid = t >> 6, lane = t & 63;
    for (int base0 = 0; base0 < EC; base0 += 256) {
        int i = base0 + t;
        float nb, bo;
        compute_vals(xr[i], br[i], gmax, bp, &nb, &bo);
        bool eq = (map_f(USE_NB ? nb : bo) == u_t);
        unsigned long long bal = __ballot(eq);
        if (lane == 0) aux[2 + wid] = (unsigned)__popcll(bal);
        __syncthreads();
        unsigned run = aux[6];
        unsigned wpre = 0;
        for (int w = 0; w < wid; ++w) wpre += aux[2 + w];
        if (eq) {
            unsigned r = run + wpre + (unsigned)__popcll(bal & ((1ull << lane) - 1ull));
            if (r == ties - 1) aux[7] = (unsigned)i;
        }
        __syncthreads();
        if (t == 0) aux[6] = run + aux[2] + aux[3] + aux[4] + aux[5];
        __syncthreads();
        if (aux[6] >= ties) break;
    }
    if (t == 0) { *ut_out = u_t; *cut_out = aux[7]; }
}

// ---------------- Kernel: zero scratch header + per-block max of x ----------------
__global__ __launch_bounds__(256) void kinit(const float4* __restrict__ x4,
                                             unsigned* __restrict__ ws) {
    if (blockIdx.x == 0)
        for (int i = threadIdx.x; i < 1024; i += 256) ws[i] = 0u;
    unsigned m = 0;
    const int nvec = BR * EC / 4;
    int stride = gridDim.x * 256;
    for (int v = blockIdx.x * 256 + threadIdx.x; v < nvec; v += stride) {
        float4 xv = x4[v];
        m = umax_(m, map_f(xv.x)); m = umax_(m, map_f(xv.y));
        m = umax_(m, map_f(xv.z)); m = umax_(m, map_f(xv.w));
    }
    for (int off = 32; off; off >>= 1) m = umax_(m, __shfl_down(m, off, 64));
    __shared__ unsigned sm[4];
    if ((threadIdx.x & 63) == 0) sm[threadIdx.x >> 6] = m;
    __syncthreads();
    if (threadIdx.x == 0)
        ws[WS_BMAX + blockIdx.x] = umax_(umax_(sm[0], sm[1]), umax_(sm[2], sm[3]));
}

// ---------------- Kernel: reduce gmax + sampled threshold per row ----------------
__global__ __launch_bounds__(256) void ktl(const float* __restrict__ x,
                                           const float* __restrict__ bt,
                                           const float* __restrict__ sp,
                                           const float* __restrict__ bp_p,
                                           unsigned* __restrict__ ws) {
    __shared__ unsigned su[NS];
    __shared__ unsigned hist[256], scan[256], sb[2], sgm[4];
    int t = threadIdx.x, row = blockIdx.x;
    // reduce 1024 per-block maxima
    unsigned m = 0;
    for (int i = t; i < 1024; i += 256) m = umax_(m, ws[WS_BMAX + i]);
    for (int off = 32; off; off >>= 1) m = umax_(m, __shfl_down(m, off, 64));
    if ((t & 63) == 0) sgm[t >> 6] = m;
    __syncthreads();
    unsigned gmu = umax_(umax_(sgm[0], sgm[1]), umax_(sgm[2], sgm[3]));
    if (row == 0 && t == 0) ws[WS_GMAX] = gmu;
    float gmax = unmap_f(gmu);
    float bp = *bp_p;
    // sample 41 chunks of 64 consecutive elements
    const float* xr = x + (size_t)row * EC;
    const float* br = bt + (size_t)row * EC;
    for (int s = t; s < NS; s += 256) {
        int idx = (s >> 6) * SSTRIDE + (s & 63);
        float nb, bo;
        compute_vals(xr[idx], br[idx], gmax, bp, &nb, &bo);
        su[s] = map_f(bo);
    }
    __syncthreads();
    unsigned K = calc_K(sp);
    unsigned R = (unsigned)ceilf(2.0f * (float)NS * (float)K / (float)EC);
    if (R < 32) R = 32;
    if (R > NS) R = NS;
    unsigned krem;
    unsigned tlo = lds_radix_select(su, NS, R, hist, scan, sb, t, &krem);
    if (t == 0) ws[WS_TLO + row] = tlo;
}

// ---------------- Kernel: collect candidates u > t_lo + exact count ----------------
__global__ __launch_bounds__(256) void kcollect(const float4* __restrict__ x4,
                                                const float4* __restrict__ bt4,
                                                const float* __restrict__ bp_p,
                                                unsigned* __restrict__ ws) {
    __shared__ unsigned lu[LCAP], li[LCAP];
    __shared__ unsigned lcnt, gbase;
    if (threadIdx.x == 0) lcnt = 0;
    int row = blockIdx.x >> 4;
    int chunk = blockIdx.x & (CHUNKS - 1);
    unsigned tlo = ws[WS_TLO + row];
    float gmax = unmap_f(ws[WS_GMAX]);
    float bp = *bp_p;
    unsigned* cu = ws + CAND_U_OFF + (size_t)row * CAP;
    unsigned* ci = ws + CAND_I_OFF + (size_t)row * CAP;
    size_t base = (size_t)row * (EC / 4) + (size_t)chunk * CHUNK_V;
    int ebase = chunk * (EC / CHUNKS);
    __syncthreads();
    for (int v = threadIdx.x; v < CHUNK_V; v += 256) {
        float4 xv = x4[base + v];
        float4 bv = bt4[base + v];
        float xs[4] = {xv.x, xv.y, xv.z, xv.w};
        float bs[4] = {bv.x, bv.y, bv.z, bv.w};
        #pragma unroll
        for (int j = 0; j < 4; ++j) {
            float nb, bo;
            compute_vals(xs[j], bs[j], gmax, bp, &nb, &bo);
            unsigned u = map_f(bo);
            if (u > tlo) {
                unsigned p = atomicAdd(&lcnt, 1u);
                if (p < LCAP) {
                    lu[p] = u; li[p] = (unsigned)(ebase + v * 4 + j);
                } else {  // overflow fallback (rare)
                    unsigned gp = atomicAdd(&ws[WS_CCNT + row], 1u);
                    if (gp < CAP) { cu[gp] = u; ci[gp] = (unsigned)(ebase + v * 4 + j); }
                }
            }
        }
    }
    __syncthreads();
    unsigned n = lcnt < LCAP ? lcnt : LCAP;
    if (threadIdx.x == 0) gbase = atomicAdd(&ws[WS_CCNT + row], n);
    __syncthreads();
    unsigned gb = gbase;
    for (unsigned i = threadIdx.x; i < n; i += 256) {
        unsigned gp = gb + i;
        if (gp < CAP) { cu[gp] = lu[i]; ci[gp] = li[i]; }
    }
}

// ---------------- Kernel: exact rank-K select + stable tie-cut ----------------
__global__ __launch_bounds__(256) void kfinal(const float* __restrict__ x,
                                              const float* __restrict__ bt,
                                              const float* __restrict__ sp,
                                              const float* __restrict__ bp_p,
                                              unsigned* __restrict__ ws) {
    int row = blockIdx.x;
    int t = threadIdx.x;
    unsigned n = ws[WS_CCNT + row];
    unsigned K = calc_K(sp);
    float gmax = unmap_f(ws[WS_GMAX]);
    float bp = *bp_p;
    __shared__ unsigned su[CAP];
    __shared__ unsigned hist[256], scan[256], sb[2];
    __shared__ unsigned marr[256];
    __shared__ unsigned mcnt;
    __shared__ unsigned aux[8];
    if (n >= K && n <= CAP) {
        // fast path: exact select among candidates (rank K overall == rank K here)
        const unsigned* cu = ws + CAND_U_OFF + (size_t)row * CAP;
        const unsigned* ci = ws + CAND_I_OFF + (size_t)row * CAP;
        for (unsigned i = t; i < n; i += 256) su[i] = cu[i];
        if (t == 0) mcnt = 0;
        __syncthreads();
        unsigned krem2;
        unsigned u_t = lds_radix_select(su, n, K, hist, scan, sb, t, &krem2);
        for (unsigned i = t; i < n; i += 256)
            if (su[i] == u_t) {
                unsigned p = atomicAdd(&mcnt, 1u);
                if (p < 256) marr[p] = ci[i];
            }
        __syncthreads();
        unsigned m = mcnt;
        if (m <= 256) {
            for (unsigned i = t; i < m; i += 256) {
                unsigned myidx = marr[i];
                unsigned r = 0;
                for (unsigned j = 0; j < m; ++j) r += (marr[j] < myidx) ? 1u : 0u;
                if (r == krem2 - 1) { ws[WS_UT + row] = u_t; ws[WS_CUT + row] = myidx; }
            }
        } else {  // pathological tie overflow: correct slow path
            for (unsigned i = t; i < n; i += 256) {
                if (su[i] == u_t) {
                    unsigned myidx = ci[i];
                    unsigned r = 0;
                    for (unsigned j = 0; j < n; ++j)
                        if (su[j] == u_t && ci[j] < myidx) ++r;
                    if (r == krem2 - 1) { ws[WS_UT + row] = u_t; ws[WS_CUT + row] = myidx; }
                }
            }
        }
    } else {
        // estimate failed (never for this data): exact full-row select
        row_select_full<0>(x + (size_t)row * EC, bt + (size_t)row * EC, gmax, bp, K,
                           hist, aux, t, &ws[WS_UT + row], &ws[WS_CUT + row]);
    }
}

// ---------------- Kernel: mark + write both outputs + count active ----------------
__global__ void kmark(const float4* __restrict__ x4, const float4* __restrict__ bt4,
                      const float* __restrict__ bp_p, unsigned* ws,
                      nf4* __restrict__ out4, nf4* __restrict__ fb4) {
    float gmax = unmap_f(ws[WS_GMAX]);
    float bp = *bp_p;
    unsigned cnt = 0;
    const size_t nvec = (size_t)BR * EC / 4;
    size_t stride = (size_t)gridDim.x * blockDim.x;
    for (size_t v = (size_t)blockIdx.x * blockDim.x + threadIdx.x; v < nvec; v += stride) {
        size_t e0 = v << 2;
        int row = (int)(e0 >> 17);
        int col = (int)(e0 & (size_t)(EC - 1));
        unsigned u_t = ws[WS_UT + row];
        int cut = (int)ws[WS_CUT + row];
        float4 xv = x4[v], bv = bt4[v];
        float xarr[4] = {xv.x, xv.y, xv.z, xv.w};
        float barr[4] = {bv.x, bv.y, bv.z, bv.w};
        nf4 o, f;
        #pragma unroll
        for (int j = 0; j < 4; ++j) {
            float nb, bo;
            compute_vals(xarr[j], barr[j], gmax, bp, &nb, &bo);
            unsigned u = map_f(bo);
            bool sel = (u > u_t) || ((u == u_t) && ((col + j) <= cut));
            bool saved = sel && (u > 0x80000000u);  // boosted > 0
            o[j] = saved ? 1.0f : 0.0f;
            f[j] = saved ? 0.0f : nb;
            cnt += saved ? 1u : 0u;
        }
        __builtin_nontemporal_store(o, &out4[v]);
        __builtin_nontemporal_store(f, &fb4[v]);
    }
    for (int off = 32; off; off >>= 1) cnt += __shfl_down(cnt, off, 64);
    __shared__ unsigned sc;
    if (threadIdx.x == 0) sc = 0;
    __syncthreads();
    if ((threadIdx.x & 63) == 0) atomicAdd(&sc, cnt);
    __syncthreads();
    if (threadIdx.x == 0) atomicAdd(&ws[WS_ACTIVE], sc);
}

// ---------------- Correction branch: per-row select on new_boost (gated, dead) ----
__global__ __launch_bounds__(256) void kselect_nb(const float* __restrict__ x,
                                                  const float* __restrict__ bt,
                                                  const float* __restrict__ sp,
                                                  const float* __restrict__ bp_p,
                                                  unsigned* ws) {
    float min_active = floorf(sp[0] * (float)EC);
    float active = (float)ws[WS_ACTIVE];
    if (!(active < min_active)) return;   // WS_TOACT stays 0 (kinit)
    unsigned K = (unsigned)ceilf(min_active - active);
    if (blockIdx.x == 0 && threadIdx.x == 0) ws[WS_TOACT] = K;
    if (K > EC) K = EC;
    int row = blockIdx.x;
    float gmax = unmap_f(ws[WS_GMAX]);
    float bp = *bp_p;
    __shared__ unsigned hist[256];
    __shared__ unsigned aux[8];
    row_select_full<1>(x + (size_t)row * EC, bt + (size_t)row * EC, gmax, bp, K,
                       hist, aux, threadIdx.x, &ws[WS_UT2 + row], &ws[WS_CUT2 + row]);
}

// ---------------- Correction apply (gated, dead here) ----------------
__global__ void kfix(const float4* __restrict__ x4, const float4* __restrict__ bt4,
                     const float* __restrict__ bp_p, const unsigned* __restrict__ ws,
                     float* __restrict__ out, float* __restrict__ fb) {
    if (ws[WS_TOACT] == 0) return;
    float gmax = unmap_f(ws[WS_GMAX]);
    float bp = *bp_p;
    const size_t nvec = (size_t)BR * EC / 4;
    size_t stride = (size_t)gridDim.x * blockDim.x;
    for (size_t v = (size_t)blockIdx.x * blockDim.x + threadIdx.x; v < nvec; v += stride) {
        size_t e0 = v << 2;
        int row = (int)(e0 >> 17);
        int col = (int)(e0 & (size_t)(EC - 1));
        unsigned u_t = ws[WS_UT2 + row];
        int cut = (int)ws[WS_CUT2 + row];
        float4 xv = x4[v], bv = bt4[v];
        float xarr[4] = {xv.x, xv.y, xv.z, xv.w};
        float barr[4] = {bv.x, bv.y, bv.z, bv.w};
        #pragma unroll
        for (int j = 0; j < 4; ++j) {
            float nb, bo;
            compute_vals(xarr[j], barr[j], gmax, bp, &nb, &bo);
            unsigned u = map_f(nb);
            if (u > u_t || (u == u_t && (col + j) <= cut)) {
                out[e0 + j] = 1.0f;
                fb[e0 + j] = 0.0f;
            }
        }
    }
}

extern "C" void kernel_launch(void* const* d_in, const int* in_sizes, int n_in,
                              void* d_out, int out_size, void* d_ws, size_t ws_size,
                              hipStream_t stream) {
    const float* x  = (const float*)d_in[0];
    const float* bt = (const float*)d_in[1];
    const float* sp = (const float*)d_in[2];
    const float* bp = (const float*)d_in[3];
    float* out = (float*)d_out;
    float* fb  = out + (size_t)BR * EC;
    unsigned* ws = (unsigned*)d_ws;

    kinit<<<1024, 256, 0, stream>>>((const float4*)x, ws);
    ktl<<<BR, 256, 0, stream>>>(x, bt, sp, bp, ws);
    kcollect<<<BR * CHUNKS, 256, 0, stream>>>((const float4*)x, (const float4*)bt, bp, ws);
    kfinal<<<BR, 256, 0, stream>>>(x, bt, sp, bp, ws);
    kmark<<<2048, 256, 0, stream>>>((const float4*)x, (const float4*)bt, bp, ws,
                                    (nf4*)out, (nf4*)fb);
    kselect_nb<<<BR, 256, 0, stream>>>(x, bt, sp, bp, ws);
    kfix<<<2048, 256, 0, stream>>>((const float4*)x, (const float4*)bt, bp, ws, out, fb);
}

// Round 11
// 77.544 us; speedup vs baseline: 12.1245x; 1.2542x over previous
//
#include <hip/hip_runtime.h>

#define BR 64
#define EC 131072
#define CAP 8192
#define LCAP 1024
#define CHUNKS 16
#define CHUNK_V (EC / CHUNKS / 4)   // float4 per chunk = 2048
#define NSCH 41
#define NS (NSCH * 64)              // 2624 samples per row
#define SSTRIDE 3197                // 40*3197+63 = 127943 < EC
#define BINS 4096

typedef float nf4 __attribute__((ext_vector_type(4)));   // native vec for nontemporal

// ws word-offset layout
#define WS_GMAX 0
#define WS_ACTIVE 1
#define WS_TOACT 2
#define WS_UT 136      // +row
#define WS_CUT 200     // +row
#define WS_CCNT 264    // +row
#define WS_UT2 512     // +row (correction branch)
#define WS_CUT2 576    // +row
#define WS_BMAX 1024   // +1024 per-block maxima (written unconditionally)
#define CAND_U_OFF 4096
#define CAND_I_OFF (CAND_U_OFF + BR * CAP)

// Monotonic float->uint mapping (order-preserving, bijective)
__device__ __forceinline__ unsigned map_f(float f) {
    unsigned b = __float_as_uint(f);
    return (b & 0x80000000u) ? ~b : (b | 0x80000000u);
}
__device__ __forceinline__ float unmap_f(unsigned u) {
    unsigned b = (u & 0x80000000u) ? (u & 0x7FFFFFFFu) : ~u;
    return __uint_as_float(b);
}

// EXACT numpy-op-sequence value computation; contract(off) so every kernel
// computes bit-identical values.
__device__ __forceinline__ void compute_vals(float x, float bt, float gmax, float bp,
                                             float* nb, float* bo) {
#pragma clang fp contract(off)
    float q = x / gmax;
    float t = 1.0f - q;
    float p = t * bp;
    float nbv = bt + p;
    *nb = nbv;
    *bo = fmaxf(x, 0.0f) + nbv;
}

__device__ __forceinline__ unsigned umax_(unsigned a, unsigned b) { return a > b ? a : b; }

__device__ __forceinline__ unsigned calc_K(const float* sp) {
    unsigned K = (unsigned)ceilf(sp[1] * (float)EC);
    if (K > EC) K = EC;
    if (K == 0) K = 1;
    return K;
}

// Radix select (descending rank K) over n values in LDS array su (full 32-bit).
__device__ unsigned lds_radix_select(const unsigned* su, unsigned n, unsigned K,
                                     unsigned* hist, unsigned* scan, unsigned* sb,
                                     int t, unsigned* krem) {
    unsigned pv = 0, Kp = K;
    for (int pass = 0; pass < 4; ++pass) {
        int shift = 24 - 8 * pass;
        hist[t] = 0;
        __syncthreads();
        for (unsigned i = t; i < n; i += 256) {
            unsigned u = su[i];
            bool match = (pass == 0) || ((u >> (shift + 8)) == (pv >> (shift + 8)));
            if (match) atomicAdd(&hist[(u >> shift) & 0xFFu], 1u);
        }
        __syncthreads();
        unsigned my = hist[t];
        scan[t] = my;
        __syncthreads();
        for (int off = 1; off < 256; off <<= 1) {
            unsigned v = (t + off < 256) ? scan[t + off] : 0u;
            __syncthreads();
            scan[t] += v;
            __syncthreads();
        }
        unsigned incl = scan[t], excl = incl - my;
        if (excl < Kp && incl >= Kp) {
            sb[0] = pv | ((unsigned)t << shift);
            sb[1] = Kp - excl;
        }
        __syncthreads();
        pv = sb[0];
        Kp = sb[1];
        __syncthreads();
    }
    *krem = Kp;
    return pv;
}

// Exact full-row select on bo (USE_NB=0) or nb (USE_NB=1). Returns u_t (uniform).
template<int USE_NB>
__device__ unsigned row_select_full(const float* xr, const float* br, float gmax,
                                    float bp, unsigned K, unsigned* hist,
                                    unsigned* aux, int t,
                                    unsigned* ut_out, unsigned* cut_out) {
    unsigned prefix = 0, Kp = K;
    for (int pass = 0; pass < 4; ++pass) {
        int shift = 24 - 8 * pass;
        hist[t] = 0;
        __syncthreads();
        for (int i = t; i < EC; i += 256) {
            float nb, bo;
            compute_vals(xr[i], br[i], gmax, bp, &nb, &bo);
            unsigned u = map_f(USE_NB ? nb : bo);
            bool match = (pass == 0) || ((u >> (shift + 8)) == (prefix >> (shift + 8)));
            if (match) atomicAdd(&hist[(u >> shift) & 0xFFu], 1u);
        }
        __syncthreads();
        if (t == 0) {
            unsigned cum = 0, bsel = 0, kr = Kp;
            for (int b = 255; b >= 0; --b) {
                unsigned h = hist[b];
                if (cum + h >= Kp) { bsel = (unsigned)b; kr = Kp - cum; break; }
                cum += h;
            }
            aux[0] = prefix | (bsel << shift);
            aux[1] = kr;
        }
        __syncthreads();
        prefix = aux[0];
        Kp = aux[1];
        __syncthreads();
    }
    unsigned u_t = prefix, ties = Kp;
    if (t == 0) { aux[6] = 0; aux[7] = 0xFFFFFFFFu; }
    __syncthreads();
    int wid = t >> 6, lane = t & 63;
    for (int base0 = 0; base0 < EC; base0 += 256) {
        int i = base0 + t;
        float nb, bo;
        compute_vals(xr[i], br[i], gmax, bp, &nb, &bo);
        bool eq = (map_f(USE_NB ? nb : bo) == u_t);
        unsigned long long bal = __ballot(eq);
        if (lane == 0) aux[2 + wid] = (unsigned)__popcll(bal);
        __syncthreads();
        unsigned run = aux[6];
        unsigned wpre = 0;
        for (int w = 0; w < wid; ++w) wpre += aux[2 + w];
        if (eq) {
            unsigned r = run + wpre + (unsigned)__popcll(bal & ((1ull << lane) - 1ull));
            if (r == ties - 1) aux[7] = (unsigned)i;
        }
        __syncthreads();
        if (t == 0) aux[6] = run + aux[2] + aux[3] + aux[4] + aux[5];
        __syncthreads();
        if (aux[6] >= ties) break;
    }
    if (t == 0) { *ut_out = u_t; *cut_out = aux[7]; }
    __syncthreads();
    return u_t;
}

// ---------------- Kernel A: zero scratch header + per-block max of x --------------
__global__ __launch_bounds__(256) void kA(const float4* __restrict__ x4,
                                          unsigned* __restrict__ ws) {
    if (blockIdx.x == 0)
        for (int i = threadIdx.x; i < 1024; i += 256) ws[i] = 0u;
    unsigned m = 0;
    const int nvec = BR * EC / 4;
    int stride = gridDim.x * 256;
    for (int v = blockIdx.x * 256 + threadIdx.x; v < nvec; v += stride) {
        float4 xv = x4[v];
        m = umax_(m, map_f(xv.x)); m = umax_(m, map_f(xv.y));
        m = umax_(m, map_f(xv.z)); m = umax_(m, map_f(xv.w));
    }
    for (int off = 32; off; off >>= 1) m = umax_(m, __shfl_down(m, off, 64));
    __shared__ unsigned sm[4];
    if ((threadIdx.x & 63) == 0) sm[threadIdx.x >> 6] = m;
    __syncthreads();
    if (threadIdx.x == 0)
        ws[WS_BMAX + blockIdx.x] = umax_(umax_(sm[0], sm[1]), umax_(sm[2], sm[3]));
}

// ---------------- Kernel B: gmax reduce + inline sample-threshold + collect -------
__global__ __launch_bounds__(256) void kB(const float* __restrict__ x,
                                          const float* __restrict__ bt,
                                          const float* __restrict__ sp,
                                          const float* __restrict__ bp_p,
                                          unsigned* __restrict__ ws) {
    __shared__ unsigned hist[BINS];               // 16KB
    __shared__ unsigned lu[LCAP], li[LCAP];       // 8KB
    __shared__ unsigned ssum[256], sabove[256];   // 2KB
    __shared__ unsigned sred[4];
    __shared__ unsigned stlo, slcnt, sgbase;
    int t = threadIdx.x;
    int row = blockIdx.x >> 4, chunk = blockIdx.x & (CHUNKS - 1);

    // 1) gmax from 1024 per-block maxima (redundant per block; L2-hot)
    unsigned m = 0;
    for (int i = t; i < 1024; i += 256) m = umax_(m, ws[WS_BMAX + i]);
    for (int off = 32; off; off >>= 1) m = umax_(m, __shfl_down(m, off, 64));
    if ((t & 63) == 0) sred[t >> 6] = m;
    __syncthreads();
    unsigned gmu = umax_(umax_(sred[0], sred[1]), umax_(sred[2], sred[3]));
    if (blockIdx.x == 0 && t == 0) ws[WS_GMAX] = gmu;
    float gmax = unmap_f(gmu);
    float bp = *bp_p;

    // 2) sample histogram (top-12 bits of u)
    for (int i = t; i < BINS; i += 256) hist[i] = 0;
    if (t == 0) slcnt = 0;
    __syncthreads();
    const float* xr = x + (size_t)row * EC;
    const float* br = bt + (size_t)row * EC;
    for (int s = t; s < NS; s += 256) {
        int idx = (s >> 6) * SSTRIDE + (s & 63);
        float nb, bo;
        compute_vals(xr[idx], br[idx], gmax, bp, &nb, &bo);
        atomicAdd(&hist[map_f(bo) >> 20], 1u);
    }
    __syncthreads();

    // 3) threshold = lower edge of bin holding rank-R sample (conservative)
    unsigned K = calc_K(sp);
    unsigned R = (unsigned)ceilf(1.75f * (float)NS * (float)K / (float)EC);
    if (R < 32) R = 32;
    if (R > NS) R = NS;
    unsigned hv[16];
    unsigned s = 0;
    #pragma unroll
    for (int j = 0; j < 16; ++j) { hv[j] = hist[t * 16 + j]; s += hv[j]; }
    ssum[t] = s;
    __syncthreads();
    if (t == 0) {
        unsigned acc = 0;
        for (int q = 255; q >= 0; --q) { sabove[q] = acc; acc += ssum[q]; }
    }
    __syncthreads();
    unsigned cum = sabove[t];
    for (int j = 15; j >= 0; --j) {
        unsigned h = hv[j];
        if (cum < R && cum + h >= R) stlo = ((unsigned)(t * 16 + j)) << 20;
        cum += h;
    }
    __syncthreads();
    unsigned tlo = stlo ? stlo - 1u : 0u;   // u > tlo  <=>  u >= bin lower edge

    // 4) collect this chunk's candidates (block-aggregated reservation)
    const float4* x4 = (const float4*)x;
    const float4* bt4 = (const float4*)bt;
    unsigned* cu = ws + CAND_U_OFF + (size_t)row * CAP;
    unsigned* ci = ws + CAND_I_OFF + (size_t)row * CAP;
    size_t base = (size_t)row * (EC / 4) + (size_t)chunk * CHUNK_V;
    int ebase = chunk * (EC / CHUNKS);
    for (int v = t; v < CHUNK_V; v += 256) {
        float4 xv = x4[base + v];
        float4 bv = bt4[base + v];
        float xs[4] = {xv.x, xv.y, xv.z, xv.w};
        float bs[4] = {bv.x, bv.y, bv.z, bv.w};
        #pragma unroll
        for (int j = 0; j < 4; ++j) {
            float nb, bo;
            compute_vals(xs[j], bs[j], gmax, bp, &nb, &bo);
            unsigned u = map_f(bo);
            if (u > tlo) {
                unsigned p = atomicAdd(&slcnt, 1u);
                if (p < LCAP) {
                    lu[p] = u; li[p] = (unsigned)(ebase + v * 4 + j);
                } else {  // overflow fallback (rare)
                    unsigned gp = atomicAdd(&ws[WS_CCNT + row], 1u);
                    if (gp < CAP) { cu[gp] = u; ci[gp] = (unsigned)(ebase + v * 4 + j); }
                }
            }
        }
    }
    __syncthreads();
    unsigned n = slcnt < LCAP ? slcnt : LCAP;
    if (t == 0) sgbase = atomicAdd(&ws[WS_CCNT + row], n);
    __syncthreads();
    unsigned gb = sgbase;
    for (unsigned i = t; i < n; i += 256) {
        unsigned gp = gb + i;
        if (gp < CAP) { cu[gp] = lu[i]; ci[gp] = li[i]; }
    }
}

// ---------------- Kernel C: exact rank-K select + tie-cut + active count ----------
__global__ __launch_bounds__(256) void kC(const float* __restrict__ x,
                                          const float* __restrict__ bt,
                                          const float* __restrict__ sp,
                                          const float* __restrict__ bp_p,
                                          unsigned* __restrict__ ws) {
    int row = blockIdx.x;
    int t = threadIdx.x;
    unsigned n = ws[WS_CCNT + row];
    unsigned K = calc_K(sp);
    __shared__ unsigned su[CAP];
    __shared__ unsigned hist[256], scan[256], sb[2];
    __shared__ unsigned marr[256];
    __shared__ unsigned mcnt;
    __shared__ unsigned aux[8];
    __shared__ unsigned scnt[4];
    unsigned row_active = 0;
    if (n >= K && n <= CAP) {
        const unsigned* cu = ws + CAND_U_OFF + (size_t)row * CAP;
        const unsigned* ci = ws + CAND_I_OFF + (size_t)row * CAP;
        for (unsigned i = t; i < n; i += 256) su[i] = cu[i];
        if (t == 0) mcnt = 0;
        __syncthreads();
        unsigned krem2;
        unsigned u_t = lds_radix_select(su, n, K, hist, scan, sb, t, &krem2);
        for (unsigned i = t; i < n; i += 256)
            if (su[i] == u_t) {
                unsigned p = atomicAdd(&mcnt, 1u);
                if (p < 256) marr[p] = ci[i];
            }
        __syncthreads();
        unsigned m = mcnt;
        if (m <= 256) {
            for (unsigned i = t; i < m; i += 256) {
                unsigned myidx = marr[i];
                unsigned r = 0;
                for (unsigned j = 0; j < m; ++j) r += (marr[j] < myidx) ? 1u : 0u;
                if (r == krem2 - 1) { ws[WS_UT + row] = u_t; ws[WS_CUT + row] = myidx; }
            }
        } else {  // pathological tie overflow: correct slow path
            for (unsigned i = t; i < n; i += 256) {
                if (su[i] == u_t) {
                    unsigned myidx = ci[i];
                    unsigned r = 0;
                    for (unsigned j = 0; j < n; ++j)
                        if (su[j] == u_t && ci[j] < myidx) ++r;
                    if (r == krem2 - 1) { ws[WS_UT + row] = u_t; ws[WS_CUT + row] = myidx; }
                }
            }
        }
        // active count: u_t positive -> all K selected are positive
        if (u_t > 0x80000000u) {
            row_active = K;
        } else {
            unsigned c = 0;
            for (unsigned i = t; i < n; i += 256) c += (su[i] > 0x80000000u) ? 1u : 0u;
            for (int off = 32; off; off >>= 1) c += __shfl_down(c, off, 64);
            if ((t & 63) == 0) scnt[t >> 6] = c;
            __syncthreads();
            row_active = scnt[0] + scnt[1] + scnt[2] + scnt[3];
        }
    } else {
        // estimate failed: exact full-row select
        float gmax = unmap_f(ws[WS_GMAX]);
        float bp = *bp_p;
        const float* xr = x + (size_t)row * EC;
        const float* br = bt + (size_t)row * EC;
        unsigned u_t = row_select_full<0>(xr, br, gmax, bp, K, hist, aux, t,
                                          &ws[WS_UT + row], &ws[WS_CUT + row]);
        if (u_t > 0x80000000u) {
            row_active = K;
        } else {
            unsigned c = 0;
            for (int i = t; i < EC; i += 256) {
                float nb, bo;
                compute_vals(xr[i], br[i], gmax, bp, &nb, &bo);
                c += (map_f(bo) > 0x80000000u) ? 1u : 0u;
            }
            for (int off = 32; off; off >>= 1) c += __shfl_down(c, off, 64);
            if ((t & 63) == 0) scnt[t >> 6] = c;
            __syncthreads();
            row_active = scnt[0] + scnt[1] + scnt[2] + scnt[3];
        }
    }
    if (t == 0) atomicAdd(&ws[WS_ACTIVE], row_active);
}

// ---------------- Correction branch: per-row select on new_boost (gated, dead) ----
__global__ __launch_bounds__(256) void kD(const float* __restrict__ x,
                                          const float* __restrict__ bt,
                                          const float* __restrict__ sp,
                                          const float* __restrict__ bp_p,
                                          unsigned* ws) {
    float min_active = floorf(sp[0] * (float)EC);
    float active = (float)ws[WS_ACTIVE];
    if (!(active < min_active)) return;   // WS_TOACT stays 0 (kA)
    unsigned K = (unsigned)ceilf(min_active - active);
    if (blockIdx.x == 0 && threadIdx.x == 0) ws[WS_TOACT] = K;
    if (K > EC) K = EC;
    int row = blockIdx.x;
    float gmax = unmap_f(ws[WS_GMAX]);
    float bp = *bp_p;
    __shared__ unsigned hist[256];
    __shared__ unsigned aux[8];
    row_select_full<1>(x + (size_t)row * EC, bt + (size_t)row * EC, gmax, bp, K,
                       hist, aux, threadIdx.x, &ws[WS_UT2 + row], &ws[WS_CUT2 + row]);
}

// ---------------- Kernel E: mark + correction, write both outputs ----------------
__global__ void kE(const float4* __restrict__ x4, const float4* __restrict__ bt4,
                   const float* __restrict__ bp_p, const unsigned* __restrict__ ws,
                   nf4* __restrict__ out4, nf4* __restrict__ fb4) {
    float gmax = unmap_f(ws[WS_GMAX]);
    float bp = *bp_p;
    unsigned toact = ws[WS_TOACT];
    const size_t nvec = (size_t)BR * EC / 4;
    size_t stride = (size_t)gridDim.x * blockDim.x;
    for (size_t v = (size_t)blockIdx.x * blockDim.x + threadIdx.x; v < nvec; v += stride) {
        size_t e0 = v << 2;
        int row = (int)(e0 >> 17);
        int col = (int)(e0 & (size_t)(EC - 1));
        unsigned u_t = ws[WS_UT + row];
        int cut = (int)ws[WS_CUT + row];
        float4 xv = x4[v], bv = bt4[v];
        float xarr[4] = {xv.x, xv.y, xv.z, xv.w};
        float barr[4] = {bv.x, bv.y, bv.z, bv.w};
        nf4 o, f;
        #pragma unroll
        for (int j = 0; j < 4; ++j) {
            float nb, bo;
            compute_vals(xarr[j], barr[j], gmax, bp, &nb, &bo);
            unsigned u = map_f(bo);
            bool sel = (u > u_t) || ((u == u_t) && ((col + j) <= cut));
            bool saved = sel && (u > 0x80000000u);  // boosted > 0
            o[j] = saved ? 1.0f : 0.0f;
            f[j] = saved ? 0.0f : nb;
        }
        if (toact) {   // correction branch (dead for this input, faithful)
            unsigned ut2 = ws[WS_UT2 + row];
            int cut2 = (int)ws[WS_CUT2 + row];
            #pragma unroll
            for (int j = 0; j < 4; ++j) {
                float nb, bo;
                compute_vals(xarr[j], barr[j], gmax, bp, &nb, &bo);
                unsigned u2 = map_f(nb);
                if (u2 > ut2 || (u2 == ut2 && (col + j) <= cut2)) {
                    o[j] = 1.0f;
                    f[j] = 0.0f;
                }
            }
        }
        __builtin_nontemporal_store(o, &out4[v]);
        __builtin_nontemporal_store(f, &fb4[v]);
    }
}

extern "C" void kernel_launch(void* const* d_in, const int* in_sizes, int n_in,
                              void* d_out, int out_size, void* d_ws, size_t ws_size,
                              hipStream_t stream) {
    const float* x  = (const float*)d_in[0];
    const float* bt = (const float*)d_in[1];
    const float* sp = (const float*)d_in[2];
    const float* bp = (const float*)d_in[3];
    float* out = (float*)d_out;
    float* fb  = out + (size_t)BR * EC;
    unsigned* ws = (unsigned*)d_ws;

    kA<<<1024, 256, 0, stream>>>((const float4*)x, ws);
    kB<<<BR * CHUNKS, 256, 0, stream>>>(x, bt, sp, bp, ws);
    kC<<<BR, 256, 0, stream>>>(x, bt, sp, bp, ws);
    kD<<<BR, 256, 0, stream>>>(x, bt, sp, bp, ws);
    kE<<<2048, 256, 0, stream>>>((const float4*)x, (const float4*)bt, bp, ws,
                                 (nf4*)out, (nf4*)fb);
}

// Round 12
// 76.693 us; speedup vs baseline: 12.2590x; 1.0111x over previous
//
#include <hip/hip_runtime.h>

#define BR 64
#define EC 131072
#define CAP 8192
#define LCAP 1024
#define CHUNKS 16
#define CHUNK_V (EC / CHUNKS / 4)   // float4 per chunk = 2048
#define NSCH 41
#define NS (NSCH * 64)              // 2624 samples per row
#define SSTRIDE 3197                // 40*3197+63 = 127943 < EC
#define BINS 4096

typedef float nf4 __attribute__((ext_vector_type(4)));   // native vec for nontemporal

// ws word-offset layout
#define WS_GMAX 0
#define WS_TOACT 2
#define WS_UT 136      // +row
#define WS_CUT 200     // +row
#define WS_CCNT 264    // +row
#define WS_UT2 512     // +row (correction branch)
#define WS_CUT2 576    // +row
#define WS_NPOS 640    // +row (positives per row)
#define WS_BMAX 1024   // +1024 per-block maxima (written unconditionally)
#define CAND_U_OFF 4096
#define CAND_I_OFF (CAND_U_OFF + BR * CAP)

// Monotonic float->uint mapping (order-preserving, bijective)
__device__ __forceinline__ unsigned map_f(float f) {
    unsigned b = __float_as_uint(f);
    return (b & 0x80000000u) ? ~b : (b | 0x80000000u);
}
__device__ __forceinline__ float unmap_f(unsigned u) {
    unsigned b = (u & 0x80000000u) ? (u & 0x7FFFFFFFu) : ~u;
    return __uint_as_float(b);
}

// EXACT numpy-op-sequence value computation; contract(off) so every kernel
// computes bit-identical values.
__device__ __forceinline__ void compute_vals(float x, float bt, float gmax, float bp,
                                             float* nb, float* bo) {
#pragma clang fp contract(off)
    float q = x / gmax;
    float t = 1.0f - q;
    float p = t * bp;
    float nbv = bt + p;
    *nb = nbv;
    *bo = fmaxf(x, 0.0f) + nbv;
}

__device__ __forceinline__ unsigned umax_(unsigned a, unsigned b) { return a > b ? a : b; }
__device__ __forceinline__ unsigned umin_(unsigned a, unsigned b) { return a < b ? a : b; }

__device__ __forceinline__ unsigned calc_K(const float* sp) {
    unsigned K = (unsigned)ceilf(sp[1] * (float)EC);
    if (K > EC) K = EC;
    if (K == 0) K = 1;
    return K;
}

// Radix select (descending rank K) over n values in LDS array su (full 32-bit).
__device__ unsigned lds_radix_select(const unsigned* su, unsigned n, unsigned K,
                                     unsigned* hist, unsigned* scan, unsigned* sb,
                                     int t, unsigned* krem) {
    unsigned pv = 0, Kp = K;
    for (int pass = 0; pass < 4; ++pass) {
        int shift = 24 - 8 * pass;
        hist[t] = 0;
        __syncthreads();
        for (unsigned i = t; i < n; i += 256) {
            unsigned u = su[i];
            bool match = (pass == 0) || ((u >> (shift + 8)) == (pv >> (shift + 8)));
            if (match) atomicAdd(&hist[(u >> shift) & 0xFFu], 1u);
        }
        __syncthreads();
        unsigned my = hist[t];
        scan[t] = my;
        __syncthreads();
        for (int off = 1; off < 256; off <<= 1) {
            unsigned v = (t + off < 256) ? scan[t + off] : 0u;
            __syncthreads();
            scan[t] += v;
            __syncthreads();
        }
        unsigned incl = scan[t], excl = incl - my;
        if (excl < Kp && incl >= Kp) {
            sb[0] = pv | ((unsigned)t << shift);
            sb[1] = Kp - excl;
        }
        __syncthreads();
        pv = sb[0];
        Kp = sb[1];
        __syncthreads();
    }
    *krem = Kp;
    return pv;
}

// Exact full-row select on bo (USE_NB=0) or nb (USE_NB=1). Returns u_t (uniform).
template<int USE_NB>
__device__ unsigned row_select_full(const float* xr, const float* br, float gmax,
                                    float bp, unsigned K, unsigned* hist,
                                    unsigned* aux, int t,
                                    unsigned* ut_out, unsigned* cut_out) {
    unsigned prefix = 0, Kp = K;
    for (int pass = 0; pass < 4; ++pass) {
        int shift = 24 - 8 * pass;
        hist[t] = 0;
        __syncthreads();
        for (int i = t; i < EC; i += 256) {
            float nb, bo;
            compute_vals(xr[i], br[i], gmax, bp, &nb, &bo);
            unsigned u = map_f(USE_NB ? nb : bo);
            bool match = (pass == 0) || ((u >> (shift + 8)) == (prefix >> (shift + 8)));
            if (match) atomicAdd(&hist[(u >> shift) & 0xFFu], 1u);
        }
        __syncthreads();
        if (t == 0) {
            unsigned cum = 0, bsel = 0, kr = Kp;
            for (int b = 255; b >= 0; --b) {
                unsigned h = hist[b];
                if (cum + h >= Kp) { bsel = (unsigned)b; kr = Kp - cum; break; }
                cum += h;
            }
            aux[0] = prefix | (bsel << shift);
            aux[1] = kr;
        }
        __syncthreads();
        prefix = aux[0];
        Kp = aux[1];
        __syncthreads();
    }
    unsigned u_t = prefix, ties = Kp;
    if (t == 0) { aux[6] = 0; aux[7] = 0xFFFFFFFFu; }
    __syncthreads();
    int wid = t >> 6, lane = t & 63;
    for (int base0 = 0; base0 < EC; base0 += 256) {
        int i = base0 + t;
        float nb, bo;
        compute_vals(xr[i], br[i], gmax, bp, &nb, &bo);
        bool eq = (map_f(USE_NB ? nb : bo) == u_t);
        unsigned long long bal = __ballot(eq);
        if (lane == 0) aux[2 + wid] = (unsigned)__popcll(bal);
        __syncthreads();
        unsigned run = aux[6];
        unsigned wpre = 0;
        for (int w = 0; w < wid; ++w) wpre += aux[2 + w];
        if (eq) {
            unsigned r = run + wpre + (unsigned)__popcll(bal & ((1ull << lane) - 1ull));
            if (r == ties - 1) aux[7] = (unsigned)i;
        }
        __syncthreads();
        if (t == 0) aux[6] = run + aux[2] + aux[3] + aux[4] + aux[5];
        __syncthreads();
        if (aux[6] >= ties) break;
    }
    if (t == 0) { *ut_out = u_t; *cut_out = aux[7]; }
    __syncthreads();
    return u_t;
}

// ---------------- Kernel A: zero scratch header + per-block max of x --------------
__global__ __launch_bounds__(256) void kA(const float4* __restrict__ x4,
                                          unsigned* __restrict__ ws) {
    if (blockIdx.x == 0)
        for (int i = threadIdx.x; i < 1024; i += 256) ws[i] = 0u;
    unsigned m = 0;
    const int nvec = BR * EC / 4;
    int stride = gridDim.x * 256;
    for (int v = blockIdx.x * 256 + threadIdx.x; v < nvec; v += stride) {
        float4 xv = x4[v];
        m = umax_(m, map_f(xv.x)); m = umax_(m, map_f(xv.y));
        m = umax_(m, map_f(xv.z)); m = umax_(m, map_f(xv.w));
    }
    for (int off = 32; off; off >>= 1) m = umax_(m, __shfl_down(m, off, 64));
    __shared__ unsigned sm[4];
    if ((threadIdx.x & 63) == 0) sm[threadIdx.x >> 6] = m;
    __syncthreads();
    if (threadIdx.x == 0)
        ws[WS_BMAX + blockIdx.x] = umax_(umax_(sm[0], sm[1]), umax_(sm[2], sm[3]));
}

// ---------------- Kernel B: gmax reduce + sample-threshold + collect + npos -------
__global__ __launch_bounds__(256) void kB(const float* __restrict__ x,
                                          const float* __restrict__ bt,
                                          const float* __restrict__ sp,
                                          const float* __restrict__ bp_p,
                                          unsigned* __restrict__ ws) {
    __shared__ unsigned hist[BINS];               // 16KB
    __shared__ unsigned lu[LCAP], li[LCAP];       // 8KB
    __shared__ unsigned ssum[256], sabove[256];   // 2KB
    __shared__ unsigned sred[4];
    __shared__ unsigned stlo, slcnt, sgbase;
    int t = threadIdx.x;
    int row = blockIdx.x >> 4, chunk = blockIdx.x & (CHUNKS - 1);

    // 1) gmax from 1024 per-block maxima (redundant per block; L2-hot)
    unsigned m = 0;
    for (int i = t; i < 1024; i += 256) m = umax_(m, ws[WS_BMAX + i]);
    for (int off = 32; off; off >>= 1) m = umax_(m, __shfl_down(m, off, 64));
    if ((t & 63) == 0) sred[t >> 6] = m;
    __syncthreads();
    unsigned gmu = umax_(umax_(sred[0], sred[1]), umax_(sred[2], sred[3]));
    if (blockIdx.x == 0 && t == 0) ws[WS_GMAX] = gmu;
    float gmax = unmap_f(gmu);
    float bp = *bp_p;

    // 2) sample histogram (top-12 bits of u)
    for (int i = t; i < BINS; i += 256) hist[i] = 0;
    if (t == 0) slcnt = 0;
    __syncthreads();
    const float* xr = x + (size_t)row * EC;
    const float* br = bt + (size_t)row * EC;
    for (int s = t; s < NS; s += 256) {
        int idx = (s >> 6) * SSTRIDE + (s & 63);
        float nb, bo;
        compute_vals(xr[idx], br[idx], gmax, bp, &nb, &bo);
        atomicAdd(&hist[map_f(bo) >> 20], 1u);
    }
    __syncthreads();

    // 3) threshold = lower edge of bin holding rank-R sample (conservative)
    unsigned K = calc_K(sp);
    unsigned R = (unsigned)ceilf(1.75f * (float)NS * (float)K / (float)EC);
    if (R < 32) R = 32;
    if (R > NS) R = NS;
    unsigned hv[16];
    unsigned s = 0;
    #pragma unroll
    for (int j = 0; j < 16; ++j) { hv[j] = hist[t * 16 + j]; s += hv[j]; }
    ssum[t] = s;
    __syncthreads();
    if (t == 0) {
        unsigned acc = 0;
        for (int q = 255; q >= 0; --q) { sabove[q] = acc; acc += ssum[q]; }
    }
    __syncthreads();
    unsigned cum = sabove[t];
    for (int j = 15; j >= 0; --j) {
        unsigned h = hv[j];
        if (cum < R && cum + h >= R) stlo = ((unsigned)(t * 16 + j)) << 20;
        cum += h;
    }
    __syncthreads();
    unsigned tlo = stlo ? stlo - 1u : 0u;   // u > tlo  <=>  u >= bin lower edge

    // 4) collect this chunk's candidates + count positives (boosted > 0)
    const float4* x4 = (const float4*)x;
    const float4* bt4 = (const float4*)bt;
    unsigned* cu = ws + CAND_U_OFF + (size_t)row * CAP;
    unsigned* ci = ws + CAND_I_OFF + (size_t)row * CAP;
    size_t base = (size_t)row * (EC / 4) + (size_t)chunk * CHUNK_V;
    int ebase = chunk * (EC / CHUNKS);
    unsigned posc = 0;
    for (int v = t; v < CHUNK_V; v += 256) {
        float4 xv = x4[base + v];
        float4 bv = bt4[base + v];
        float xs[4] = {xv.x, xv.y, xv.z, xv.w};
        float bs[4] = {bv.x, bv.y, bv.z, bv.w};
        #pragma unroll
        for (int j = 0; j < 4; ++j) {
            float nb, bo;
            compute_vals(xs[j], bs[j], gmax, bp, &nb, &bo);
            unsigned u = map_f(bo);
            posc += (u > 0x80000000u) ? 1u : 0u;
            if (u > tlo) {
                unsigned p = atomicAdd(&slcnt, 1u);
                if (p < LCAP) {
                    lu[p] = u; li[p] = (unsigned)(ebase + v * 4 + j);
                } else {  // overflow fallback (rare)
                    unsigned gp = atomicAdd(&ws[WS_CCNT + row], 1u);
                    if (gp < CAP) { cu[gp] = u; ci[gp] = (unsigned)(ebase + v * 4 + j); }
                }
            }
        }
    }
    for (int off = 32; off; off >>= 1) posc += __shfl_down(posc, off, 64);
    if ((t & 63) == 0) sred[t >> 6] = posc;
    __syncthreads();
    if (t == 0) atomicAdd(&ws[WS_NPOS + row], sred[0] + sred[1] + sred[2] + sred[3]);
    __syncthreads();
    unsigned n = slcnt < LCAP ? slcnt : LCAP;
    if (t == 0) sgbase = atomicAdd(&ws[WS_CCNT + row], n);
    __syncthreads();
    unsigned gb = sgbase;
    for (unsigned i = t; i < n; i += 256) {
        unsigned gp = gb + i;
        if (gp < CAP) { cu[gp] = lu[i]; ci[gp] = li[i]; }
    }
}

// ---------------- Kernel C: exact rank-K select + tie-cut + gated correction ------
// active = sum_r min(K, npos[r])  [exact: tie-cut selects exactly K; if npos>=K the
// K-th largest is positive -> saved=K; else all positives selected -> saved=npos]
__global__ __launch_bounds__(256) void kC(const float* __restrict__ x,
                                          const float* __restrict__ bt,
                                          const float* __restrict__ sp,
                                          const float* __restrict__ bp_p,
                                          unsigned* __restrict__ ws) {
    int row = blockIdx.x;
    int t = threadIdx.x;
    unsigned n = ws[WS_CCNT + row];
    unsigned K = calc_K(sp);
    float gmax = unmap_f(ws[WS_GMAX]);
    float bp = *bp_p;
    __shared__ unsigned su[CAP];
    __shared__ unsigned hist[256], scan[256], sb[2];
    __shared__ unsigned marr[256];
    __shared__ unsigned mcnt;
    __shared__ unsigned aux[8];
    __shared__ unsigned sact;
    if (n >= K && n <= CAP) {
        const unsigned* cu = ws + CAND_U_OFF + (size_t)row * CAP;
        const unsigned* ci = ws + CAND_I_OFF + (size_t)row * CAP;
        for (unsigned i = t; i < n; i += 256) su[i] = cu[i];
        if (t == 0) mcnt = 0;
        __syncthreads();
        unsigned krem2;
        unsigned u_t = lds_radix_select(su, n, K, hist, scan, sb, t, &krem2);
        for (unsigned i = t; i < n; i += 256)
            if (su[i] == u_t) {
                unsigned p = atomicAdd(&mcnt, 1u);
                if (p < 256) marr[p] = ci[i];
            }
        __syncthreads();
        unsigned m = mcnt;
        if (m <= 256) {
            for (unsigned i = t; i < m; i += 256) {
                unsigned myidx = marr[i];
                unsigned r = 0;
                for (unsigned j = 0; j < m; ++j) r += (marr[j] < myidx) ? 1u : 0u;
                if (r == krem2 - 1) { ws[WS_UT + row] = u_t; ws[WS_CUT + row] = myidx; }
            }
        } else {  // pathological tie overflow: correct slow path
            for (unsigned i = t; i < n; i += 256) {
                if (su[i] == u_t) {
                    unsigned myidx = ci[i];
                    unsigned r = 0;
                    for (unsigned j = 0; j < n; ++j)
                        if (su[j] == u_t && ci[j] < myidx) ++r;
                    if (r == krem2 - 1) { ws[WS_UT + row] = u_t; ws[WS_CUT + row] = myidx; }
                }
            }
        }
    } else {
        // estimate failed: exact full-row select
        row_select_full<0>(x + (size_t)row * EC, bt + (size_t)row * EC, gmax, bp, K,
                           hist, aux, t, &ws[WS_UT + row], &ws[WS_CUT + row]);
    }

    // ---- global active + gated correction (formerly kernel kD) ----
    unsigned act = 0;
    if (t < 64) act = umin_(K, ws[WS_NPOS + t]);
    for (int off = 32; off; off >>= 1) act += __shfl_down(act, off, 64);
    if (t == 0) sact = act;
    __syncthreads();
    float active = (float)sact;
    float min_active = floorf(sp[0] * (float)EC);
    if (active < min_active) {
        unsigned K2 = (unsigned)ceilf(min_active - active);
        if (row == 0 && t == 0) ws[WS_TOACT] = K2;
        if (K2 > EC) K2 = EC;
        row_select_full<1>(x + (size_t)row * EC, bt + (size_t)row * EC, gmax, bp, K2,
                           hist, aux, t, &ws[WS_UT2 + row], &ws[WS_CUT2 + row]);
    }
}

// ---------------- Kernel E: mark + correction, write both outputs ----------------
__global__ void kE(const float4* __restrict__ x4, const float4* __restrict__ bt4,
                   const float* __restrict__ bp_p, const unsigned* __restrict__ ws,
                   nf4* __restrict__ out4, nf4* __restrict__ fb4) {
    float gmax = unmap_f(ws[WS_GMAX]);
    float bp = *bp_p;
    unsigned toact = ws[WS_TOACT];
    const size_t nvec = (size_t)BR * EC / 4;
    size_t stride = (size_t)gridDim.x * blockDim.x;
    for (size_t v = (size_t)blockIdx.x * blockDim.x + threadIdx.x; v < nvec; v += stride) {
        size_t e0 = v << 2;
        int row = (int)(e0 >> 17);
        int col = (int)(e0 & (size_t)(EC - 1));
        unsigned u_t = ws[WS_UT + row];
        int cut = (int)ws[WS_CUT + row];
        float4 xv = x4[v], bv = bt4[v];
        float xarr[4] = {xv.x, xv.y, xv.z, xv.w};
        float barr[4] = {bv.x, bv.y, bv.z, bv.w};
        nf4 o, f;
        #pragma unroll
        for (int j = 0; j < 4; ++j) {
            float nb, bo;
            compute_vals(xarr[j], barr[j], gmax, bp, &nb, &bo);
            unsigned u = map_f(bo);
            bool sel = (u > u_t) || ((u == u_t) && ((col + j) <= cut));
            bool saved = sel && (u > 0x80000000u);  // boosted > 0
            o[j] = saved ? 1.0f : 0.0f;
            f[j] = saved ? 0.0f : nb;
        }
        if (toact) {   // correction branch (dead for this input, faithful)
            unsigned ut2 = ws[WS_UT2 + row];
            int cut2 = (int)ws[WS_CUT2 + row];
            #pragma unroll
            for (int j = 0; j < 4; ++j) {
                float nb, bo;
                compute_vals(xarr[j], barr[j], gmax, bp, &nb, &bo);
                unsigned u2 = map_f(nb);
                if (u2 > ut2 || (u2 == ut2 && (col + j) <= cut2)) {
                    o[j] = 1.0f;
                    f[j] = 0.0f;
                }
            }
        }
        __builtin_nontemporal_store(o, &out4[v]);
        __builtin_nontemporal_store(f, &fb4[v]);
    }
}

extern "C" void kernel_launch(void* const* d_in, const int* in_sizes, int n_in,
                              void* d_out, int out_size, void* d_ws, size_t ws_size,
                              hipStream_t stream) {
    const float* x  = (const float*)d_in[0];
    const float* bt = (const float*)d_in[1];
    const float* sp = (const float*)d_in[2];
    const float* bp = (const float*)d_in[3];
    float* out = (float*)d_out;
    float* fb  = out + (size_t)BR * EC;
    unsigned* ws = (unsigned*)d_ws;

    kA<<<1024, 256, 0, stream>>>((const float4*)x, ws);
    kB<<<BR * CHUNKS, 256, 0, stream>>>(x, bt, sp, bp, ws);
    kC<<<BR, 256, 0, stream>>>(x, bt, sp, bp, ws);
    kE<<<2048, 256, 0, stream>>>((const float4*)x, (const float4*)bt, bp, ws,
                                 (nf4*)out, (nf4*)fb);
}

// Round 13
// 74.764 us; speedup vs baseline: 12.5752x; 1.0258x over previous
//
#include <hip/hip_runtime.h>

#define BR 64
#define EC 131072
#define CAP 8192
#define LCAP 1024
#define CHUNKS 16
#define CHUNK_V (EC / CHUNKS / 4)   // float4 per chunk = 2048
#define NSCH 41
#define NS (NSCH * 64)              // 2624 samples per row
#define SSTRIDE 3197                // 40*3197+63 = 127943 < EC
#define BINS 4096

typedef float nf4 __attribute__((ext_vector_type(4)));   // native vec for nontemporal

// ws word-offset layout
#define WS_GMAX 0
#define WS_CCNT 264    // +row
#define WS_NPOS 640    // +row (positives per row)
#define WS_BMAX 1024   // +1024 per-block maxima (written unconditionally)
#define CAND_U_OFF 4096
#define CAND_I_OFF (CAND_U_OFF + BR * CAP)

// Monotonic float->uint mapping (order-preserving, bijective)
__device__ __forceinline__ unsigned map_f(float f) {
    unsigned b = __float_as_uint(f);
    return (b & 0x80000000u) ? ~b : (b | 0x80000000u);
}
__device__ __forceinline__ float unmap_f(unsigned u) {
    unsigned b = (u & 0x80000000u) ? (u & 0x7FFFFFFFu) : ~u;
    return __uint_as_float(b);
}

// EXACT numpy-op-sequence value computation; contract(off) so every kernel
// computes bit-identical values.
__device__ __forceinline__ void compute_vals(float x, float bt, float gmax, float bp,
                                             float* nb, float* bo) {
#pragma clang fp contract(off)
    float q = x / gmax;
    float t = 1.0f - q;
    float p = t * bp;
    float nbv = bt + p;
    *nb = nbv;
    *bo = fmaxf(x, 0.0f) + nbv;
}

__device__ __forceinline__ unsigned umax_(unsigned a, unsigned b) { return a > b ? a : b; }
__device__ __forceinline__ unsigned umin_(unsigned a, unsigned b) { return a < b ? a : b; }

__device__ __forceinline__ unsigned calc_K(const float* sp) {
    unsigned K = (unsigned)ceilf(sp[1] * (float)EC);
    if (K > EC) K = EC;
    if (K == 0) K = 1;
    return K;
}

// Radix select (descending rank K) over n values in LDS array su (full 32-bit).
__device__ unsigned lds_radix_select(const unsigned* su, unsigned n, unsigned K,
                                     unsigned* hist, unsigned* scan, unsigned* sb,
                                     int t, unsigned* krem) {
    unsigned pv = 0, Kp = K;
    for (int pass = 0; pass < 4; ++pass) {
        int shift = 24 - 8 * pass;
        hist[t] = 0;
        __syncthreads();
        for (unsigned i = t; i < n; i += 256) {
            unsigned u = su[i];
            bool match = (pass == 0) || ((u >> (shift + 8)) == (pv >> (shift + 8)));
            if (match) atomicAdd(&hist[(u >> shift) & 0xFFu], 1u);
        }
        __syncthreads();
        unsigned my = hist[t];
        scan[t] = my;
        __syncthreads();
        for (int off = 1; off < 256; off <<= 1) {
            unsigned v = (t + off < 256) ? scan[t + off] : 0u;
            __syncthreads();
            scan[t] += v;
            __syncthreads();
        }
        unsigned incl = scan[t], excl = incl - my;
        if (excl < Kp && incl >= Kp) {
            sb[0] = pv | ((unsigned)t << shift);
            sb[1] = Kp - excl;
        }
        __syncthreads();
        pv = sb[0];
        Kp = sb[1];
        __syncthreads();
    }
    *krem = Kp;
    return pv;
}

// Exact full-row select on bo (USE_NB=0) or nb (USE_NB=1). Returns u_t (uniform);
// *cut_out (may be LDS) valid for all threads after return.
template<int USE_NB>
__device__ unsigned row_select_full(const float* xr, const float* br, float gmax,
                                    float bp, unsigned K, unsigned* hist,
                                    unsigned* aux, int t, unsigned* cut_out) {
    unsigned prefix = 0, Kp = K;
    for (int pass = 0; pass < 4; ++pass) {
        int shift = 24 - 8 * pass;
        hist[t] = 0;
        __syncthreads();
        for (int i = t; i < EC; i += 256) {
            float nb, bo;
            compute_vals(xr[i], br[i], gmax, bp, &nb, &bo);
            unsigned u = map_f(USE_NB ? nb : bo);
            bool match = (pass == 0) || ((u >> (shift + 8)) == (prefix >> (shift + 8)));
            if (match) atomicAdd(&hist[(u >> shift) & 0xFFu], 1u);
        }
        __syncthreads();
        if (t == 0) {
            unsigned cum = 0, bsel = 0, kr = Kp;
            for (int b = 255; b >= 0; --b) {
                unsigned h = hist[b];
                if (cum + h >= Kp) { bsel = (unsigned)b; kr = Kp - cum; break; }
                cum += h;
            }
            aux[0] = prefix | (bsel << shift);
            aux[1] = kr;
        }
        __syncthreads();
        prefix = aux[0];
        Kp = aux[1];
        __syncthreads();
    }
    unsigned u_t = prefix, ties = Kp;
    if (t == 0) { aux[6] = 0; aux[7] = 0xFFFFFFFFu; }
    __syncthreads();
    int wid = t >> 6, lane = t & 63;
    for (int base0 = 0; base0 < EC; base0 += 256) {
        int i = base0 + t;
        float nb, bo;
        compute_vals(xr[i], br[i], gmax, bp, &nb, &bo);
        bool eq = (map_f(USE_NB ? nb : bo) == u_t);
        unsigned long long bal = __ballot(eq);
        if (lane == 0) aux[2 + wid] = (unsigned)__popcll(bal);
        __syncthreads();
        unsigned run = aux[6];
        unsigned wpre = 0;
        for (int w = 0; w < wid; ++w) wpre += aux[2 + w];
        if (eq) {
            unsigned r = run + wpre + (unsigned)__popcll(bal & ((1ull << lane) - 1ull));
            if (r == ties - 1) aux[7] = (unsigned)i;
        }
        __syncthreads();
        if (t == 0) aux[6] = run + aux[2] + aux[3] + aux[4] + aux[5];
        __syncthreads();
        if (aux[6] >= ties) break;
    }
    if (t == 0) *cut_out = aux[7];
    __syncthreads();
    return u_t;
}

// ---------------- Kernel A: zero scratch header + per-block max of x --------------
__global__ __launch_bounds__(256) void kA(const float4* __restrict__ x4,
                                          unsigned* __restrict__ ws) {
    if (blockIdx.x == 0)
        for (int i = threadIdx.x; i < 1024; i += 256) ws[i] = 0u;
    unsigned m = 0;
    const int nvec = BR * EC / 4;
    int stride = gridDim.x * 256;
    for (int v = blockIdx.x * 256 + threadIdx.x; v < nvec; v += stride) {
        float4 xv = x4[v];
        m = umax_(m, map_f(xv.x)); m = umax_(m, map_f(xv.y));
        m = umax_(m, map_f(xv.z)); m = umax_(m, map_f(xv.w));
    }
    for (int off = 32; off; off >>= 1) m = umax_(m, __shfl_down(m, off, 64));
    __shared__ unsigned sm[4];
    if ((threadIdx.x & 63) == 0) sm[threadIdx.x >> 6] = m;
    __syncthreads();
    if (threadIdx.x == 0)
        ws[WS_BMAX + blockIdx.x] = umax_(umax_(sm[0], sm[1]), umax_(sm[2], sm[3]));
}

// -------- Kernel B: gmax + sample-threshold + collect + npos + DEFAULT outputs ----
// Writes out=0, fb=new_boost for every element (the "nothing selected" default);
// kC scatter-fixes only the ~K selected entries per row.
__global__ __launch_bounds__(256) void kB(const float* __restrict__ x,
                                          const float* __restrict__ bt,
                                          const float* __restrict__ sp,
                                          const float* __restrict__ bp_p,
                                          unsigned* __restrict__ ws,
                                          nf4* __restrict__ out4,
                                          nf4* __restrict__ fb4) {
    __shared__ unsigned hist[BINS];               // 16KB
    __shared__ unsigned lu[LCAP], li[LCAP];       // 8KB
    __shared__ unsigned ssum[256], sabove[256];   // 2KB
    __shared__ unsigned sred[4];
    __shared__ unsigned stlo, slcnt, sgbase;
    int t = threadIdx.x;
    int row = blockIdx.x >> 4, chunk = blockIdx.x & (CHUNKS - 1);

    // 1) gmax from 1024 per-block maxima (redundant per block; L2-hot)
    unsigned m = 0;
    for (int i = t; i < 1024; i += 256) m = umax_(m, ws[WS_BMAX + i]);
    for (int off = 32; off; off >>= 1) m = umax_(m, __shfl_down(m, off, 64));
    if ((t & 63) == 0) sred[t >> 6] = m;
    __syncthreads();
    unsigned gmu = umax_(umax_(sred[0], sred[1]), umax_(sred[2], sred[3]));
    if (blockIdx.x == 0 && t == 0) ws[WS_GMAX] = gmu;
    float gmax = unmap_f(gmu);
    float bp = *bp_p;

    // 2) sample histogram (top-12 bits of u)
    for (int i = t; i < BINS; i += 256) hist[i] = 0;
    if (t == 0) slcnt = 0;
    __syncthreads();
    const float* xr = x + (size_t)row * EC;
    const float* br = bt + (size_t)row * EC;
    for (int s = t; s < NS; s += 256) {
        int idx = (s >> 6) * SSTRIDE + (s & 63);
        float nb, bo;
        compute_vals(xr[idx], br[idx], gmax, bp, &nb, &bo);
        atomicAdd(&hist[map_f(bo) >> 20], 1u);
    }
    __syncthreads();

    // 3) threshold = lower edge of bin holding rank-R sample (conservative)
    unsigned K = calc_K(sp);
    unsigned R = (unsigned)ceilf(1.75f * (float)NS * (float)K / (float)EC);
    if (R < 32) R = 32;
    if (R > NS) R = NS;
    unsigned hv[16];
    unsigned s = 0;
    #pragma unroll
    for (int j = 0; j < 16; ++j) { hv[j] = hist[t * 16 + j]; s += hv[j]; }
    ssum[t] = s;
    __syncthreads();
    if (t == 0) {
        unsigned acc = 0;
        for (int q = 255; q >= 0; --q) { sabove[q] = acc; acc += ssum[q]; }
    }
    __syncthreads();
    unsigned cum = sabove[t];
    for (int j = 15; j >= 0; --j) {
        unsigned h = hv[j];
        if (cum < R && cum + h >= R) stlo = ((unsigned)(t * 16 + j)) << 20;
        cum += h;
    }
    __syncthreads();
    unsigned tlo = stlo ? stlo - 1u : 0u;   // u > tlo  <=>  u >= bin lower edge

    // 4) collect candidates + npos + write default outputs
    const float4* x4 = (const float4*)x;
    const float4* bt4 = (const float4*)bt;
    unsigned* cu = ws + CAND_U_OFF + (size_t)row * CAP;
    unsigned* ci = ws + CAND_I_OFF + (size_t)row * CAP;
    size_t base = (size_t)row * (EC / 4) + (size_t)chunk * CHUNK_V;
    int ebase = chunk * (EC / CHUNKS);
    const nf4 zo = {0.0f, 0.0f, 0.0f, 0.0f};
    unsigned posc = 0;
    for (int v = t; v < CHUNK_V; v += 256) {
        float4 xv = x4[base + v];
        float4 bv = bt4[base + v];
        float xs[4] = {xv.x, xv.y, xv.z, xv.w};
        float bs[4] = {bv.x, bv.y, bv.z, bv.w};
        nf4 fv;
        #pragma unroll
        for (int j = 0; j < 4; ++j) {
            float nb, bo;
            compute_vals(xs[j], bs[j], gmax, bp, &nb, &bo);
            unsigned u = map_f(bo);
            fv[j] = nb;
            posc += (u > 0x80000000u) ? 1u : 0u;
            if (u > tlo) {
                unsigned p = atomicAdd(&slcnt, 1u);
                if (p < LCAP) {
                    lu[p] = u; li[p] = (unsigned)(ebase + v * 4 + j);
                } else {  // overflow fallback (rare)
                    unsigned gp = atomicAdd(&ws[WS_CCNT + row], 1u);
                    if (gp < CAP) { cu[gp] = u; ci[gp] = (unsigned)(ebase + v * 4 + j); }
                }
            }
        }
        __builtin_nontemporal_store(zo, &out4[base + v]);
        __builtin_nontemporal_store(fv, &fb4[base + v]);
    }
    for (int off = 32; off; off >>= 1) posc += __shfl_down(posc, off, 64);
    if ((t & 63) == 0) sred[t >> 6] = posc;
    __syncthreads();
    if (t == 0) atomicAdd(&ws[WS_NPOS + row], sred[0] + sred[1] + sred[2] + sred[3]);
    __syncthreads();
    unsigned n = slcnt < LCAP ? slcnt : LCAP;
    if (t == 0) sgbase = atomicAdd(&ws[WS_CCNT + row], n);
    __syncthreads();
    unsigned gb = sgbase;
    for (unsigned i = t; i < n; i += 256) {
        unsigned gp = gb + i;
        if (gp < CAP) { cu[gp] = lu[i]; ci[gp] = li[i]; }
    }
}

// -------- Kernel C: exact rank-K select + tie-cut + scatter-fix + gated correction
// active = sum_r min(K, npos[r])  [exact: selection picks exactly K; if npos>=K the
// K-th largest is positive -> saved=K; else all positives selected -> saved=npos]
__global__ __launch_bounds__(256) void kC(const float* __restrict__ x,
                                          const float* __restrict__ bt,
                                          const float* __restrict__ sp,
                                          const float* __restrict__ bp_p,
                                          unsigned* __restrict__ ws,
                                          float* __restrict__ out,
                                          float* __restrict__ fb) {
    int row = blockIdx.x;
    int t = threadIdx.x;
    unsigned n = ws[WS_CCNT + row];
    unsigned K = calc_K(sp);
    float gmax = unmap_f(ws[WS_GMAX]);
    float bp = *bp_p;
    const float* xr = x + (size_t)row * EC;
    const float* br = bt + (size_t)row * EC;
    float* outr = out + (size_t)row * EC;
    float* fbr = fb + (size_t)row * EC;
    __shared__ unsigned su[CAP];
    __shared__ unsigned hist[256], scan[256], sb[2];
    __shared__ unsigned marr[256];
    __shared__ unsigned mcnt;
    __shared__ unsigned aux[8];
    __shared__ unsigned sact, scut;
    if (n >= K && n <= CAP) {
        const unsigned* cu = ws + CAND_U_OFF + (size_t)row * CAP;
        const unsigned* ci = ws + CAND_I_OFF + (size_t)row * CAP;
        for (unsigned i = t; i < n; i += 256) su[i] = cu[i];
        if (t == 0) mcnt = 0;
        __syncthreads();
        unsigned krem2;
        unsigned u_t = lds_radix_select(su, n, K, hist, scan, sb, t, &krem2);
        for (unsigned i = t; i < n; i += 256)
            if (su[i] == u_t) {
                unsigned p = atomicAdd(&mcnt, 1u);
                if (p < 256) marr[p] = ci[i];
            }
        __syncthreads();
        unsigned m = mcnt;
        if (m <= 256) {
            for (unsigned i = t; i < m; i += 256) {
                unsigned myidx = marr[i];
                unsigned r = 0;
                for (unsigned j = 0; j < m; ++j) r += (marr[j] < myidx) ? 1u : 0u;
                if (r == krem2 - 1) scut = myidx;
            }
        } else {  // pathological tie overflow: correct slow path
            for (unsigned i = t; i < n; i += 256) {
                if (su[i] == u_t) {
                    unsigned myidx = ci[i];
                    unsigned r = 0;
                    for (unsigned j = 0; j < n; ++j)
                        if (su[j] == u_t && ci[j] < myidx) ++r;
                    if (r == krem2 - 1) scut = myidx;
                }
            }
        }
        __syncthreads();
        unsigned cut = scut;
        // scatter-fix selected entries (defaults already written by kB)
        for (unsigned i = t; i < n; i += 256) {
            unsigned u = su[i], idx = ci[i];
            bool sel = (u > u_t) || ((u == u_t) && (idx <= cut));
            if (sel && u > 0x80000000u) { outr[idx] = 1.0f; fbr[idx] = 0.0f; }
        }
    } else {
        // estimate failed (never for this data): exact full-row select + full fix
        unsigned u_t = row_select_full<0>(xr, br, gmax, bp, K, hist, aux, t, &scut);
        unsigned cut = scut;
        for (int i = t; i < EC; i += 256) {
            float nb, bo;
            compute_vals(xr[i], br[i], gmax, bp, &nb, &bo);
            unsigned u = map_f(bo);
            bool sel = (u > u_t) || ((u == u_t) && ((unsigned)i <= cut));
            if (sel && u > 0x80000000u) { outr[i] = 1.0f; fbr[i] = 0.0f; }
        }
    }

    // ---- global active + gated correction branch (dead for this input) ----
    unsigned act = 0;
    if (t < 64) act = umin_(K, ws[WS_NPOS + t]);
    for (int off = 32; off; off >>= 1) act += __shfl_down(act, off, 64);
    if (t == 0) sact = act;
    __syncthreads();
    float active = (float)sact;
    float min_active = floorf(sp[0] * (float)EC);
    if (active < min_active) {
        unsigned K2 = (unsigned)ceilf(min_active - active);
        if (K2 > EC) K2 = EC;
        unsigned ut2 = row_select_full<1>(xr, br, gmax, bp, K2, hist, aux, t, &scut);
        unsigned cut2 = scut;
        for (int i = t; i < EC; i += 256) {
            float nb, bo;
            compute_vals(xr[i], br[i], gmax, bp, &nb, &bo);
            unsigned u2 = map_f(nb);
            if (u2 > ut2 || (u2 == ut2 && (unsigned)i <= cut2)) {
                outr[i] = 1.0f;
                fbr[i] = 0.0f;
            }
        }
    }
}

extern "C" void kernel_launch(void* const* d_in, const int* in_sizes, int n_in,
                              void* d_out, int out_size, void* d_ws, size_t ws_size,
                              hipStream_t stream) {
    const float* x  = (const float*)d_in[0];
    const float* bt = (const float*)d_in[1];
    const float* sp = (const float*)d_in[2];
    const float* bp = (const float*)d_in[3];
    float* out = (float*)d_out;
    float* fb  = out + (size_t)BR * EC;
    unsigned* ws = (unsigned*)d_ws;

    kA<<<1024, 256, 0, stream>>>((const float4*)x, ws);
    kB<<<BR * CHUNKS, 256, 0, stream>>>(x, bt, sp, bp, ws, (nf4*)out, (nf4*)fb);
    kC<<<BR, 256, 0, stream>>>(x, bt, sp, bp, ws, out, fb);
}

// Round 14
// 72.658 us; speedup vs baseline: 12.9397x; 1.0290x over previous
//
#include <hip/hip_runtime.h>

#define BR 64
#define EC 131072
#define CAP 8192
#define LCAP 1024
#define CHUNKS 16
#define CHUNK_V (EC / CHUNKS / 4)   // float4 per chunk = 2048
#define NSCH 41
#define NS (NSCH * 64)              // 2624 samples per row
#define SSTRIDE 3197                // 40*3197+63 = 127943 < EC
#define BINS 4096
#define BD 512                      // kB block size (8 waves)

typedef float nf4 __attribute__((ext_vector_type(4)));   // native vec for nontemporal

// ws word-offset layout
#define WS_GMAX 0
#define WS_CCNT 264    // +row
#define WS_NPOS 640    // +row (positives per row)
#define WS_BMAX 1024   // +1024 per-block maxima (written unconditionally)
#define CAND_U_OFF 4096
#define CAND_I_OFF (CAND_U_OFF + BR * CAP)

// Monotonic float->uint mapping (order-preserving, bijective)
__device__ __forceinline__ unsigned map_f(float f) {
    unsigned b = __float_as_uint(f);
    return (b & 0x80000000u) ? ~b : (b | 0x80000000u);
}
__device__ __forceinline__ float unmap_f(unsigned u) {
    unsigned b = (u & 0x80000000u) ? (u & 0x7FFFFFFFu) : ~u;
    return __uint_as_float(b);
}

// EXACT numpy-op-sequence value computation; contract(off) so every kernel
// computes bit-identical values.
__device__ __forceinline__ void compute_vals(float x, float bt, float gmax, float bp,
                                             float* nb, float* bo) {
#pragma clang fp contract(off)
    float q = x / gmax;
    float t = 1.0f - q;
    float p = t * bp;
    float nbv = bt + p;
    *nb = nbv;
    *bo = fmaxf(x, 0.0f) + nbv;
}

__device__ __forceinline__ unsigned umax_(unsigned a, unsigned b) { return a > b ? a : b; }
__device__ __forceinline__ unsigned umin_(unsigned a, unsigned b) { return a < b ? a : b; }

__device__ __forceinline__ unsigned calc_K(const float* sp) {
    unsigned K = (unsigned)ceilf(sp[1] * (float)EC);
    if (K > EC) K = EC;
    if (K == 0) K = 1;
    return K;
}

// Radix select (descending rank K) over n values in LDS array su (full 32-bit).
// 256 threads.
__device__ unsigned lds_radix_select(const unsigned* su, unsigned n, unsigned K,
                                     unsigned* hist, unsigned* scan, unsigned* sb,
                                     int t, unsigned* krem) {
    unsigned pv = 0, Kp = K;
    for (int pass = 0; pass < 4; ++pass) {
        int shift = 24 - 8 * pass;
        hist[t] = 0;
        __syncthreads();
        for (unsigned i = t; i < n; i += 256) {
            unsigned u = su[i];
            bool match = (pass == 0) || ((u >> (shift + 8)) == (pv >> (shift + 8)));
            if (match) atomicAdd(&hist[(u >> shift) & 0xFFu], 1u);
        }
        __syncthreads();
        unsigned my = hist[t];
        scan[t] = my;
        __syncthreads();
        for (int off = 1; off < 256; off <<= 1) {
            unsigned v = (t + off < 256) ? scan[t + off] : 0u;
            __syncthreads();
            scan[t] += v;
            __syncthreads();
        }
        unsigned incl = scan[t], excl = incl - my;
        if (excl < Kp && incl >= Kp) {
            sb[0] = pv | ((unsigned)t << shift);
            sb[1] = Kp - excl;
        }
        __syncthreads();
        pv = sb[0];
        Kp = sb[1];
        __syncthreads();
    }
    *krem = Kp;
    return pv;
}

// Exact full-row select on bo (USE_NB=0) or nb (USE_NB=1). 256 threads.
// Returns u_t (uniform); *cut_out (LDS) valid for all threads after return.
template<int USE_NB>
__device__ unsigned row_select_full(const float* xr, const float* br, float gmax,
                                    float bp, unsigned K, unsigned* hist,
                                    unsigned* aux, int t, unsigned* cut_out) {
    unsigned prefix = 0, Kp = K;
    for (int pass = 0; pass < 4; ++pass) {
        int shift = 24 - 8 * pass;
        hist[t] = 0;
        __syncthreads();
        for (int i = t; i < EC; i += 256) {
            float nb, bo;
            compute_vals(xr[i], br[i], gmax, bp, &nb, &bo);
            unsigned u = map_f(USE_NB ? nb : bo);
            bool match = (pass == 0) || ((u >> (shift + 8)) == (prefix >> (shift + 8)));
            if (match) atomicAdd(&hist[(u >> shift) & 0xFFu], 1u);
        }
        __syncthreads();
        if (t == 0) {
            unsigned cum = 0, bsel = 0, kr = Kp;
            for (int b = 255; b >= 0; --b) {
                unsigned h = hist[b];
                if (cum + h >= Kp) { bsel = (unsigned)b; kr = Kp - cum; break; }
                cum += h;
            }
            aux[0] = prefix | (bsel << shift);
            aux[1] = kr;
        }
        __syncthreads();
        prefix = aux[0];
        Kp = aux[1];
        __syncthreads();
    }
    unsigned u_t = prefix, ties = Kp;
    if (t == 0) { aux[6] = 0; aux[7] = 0xFFFFFFFFu; }
    __syncthreads();
    int wid = t >> 6, lane = t & 63;
    for (int base0 = 0; base0 < EC; base0 += 256) {
        int i = base0 + t;
        float nb, bo;
        compute_vals(xr[i], br[i], gmax, bp, &nb, &bo);
        bool eq = (map_f(USE_NB ? nb : bo) == u_t);
        unsigned long long bal = __ballot(eq);
        if (lane == 0) aux[2 + wid] = (unsigned)__popcll(bal);
        __syncthreads();
        unsigned run = aux[6];
        unsigned wpre = 0;
        for (int w = 0; w < wid; ++w) wpre += aux[2 + w];
        if (eq) {
            unsigned r = run + wpre + (unsigned)__popcll(bal & ((1ull << lane) - 1ull));
            if (r == ties - 1) aux[7] = (unsigned)i;
        }
        __syncthreads();
        if (t == 0) aux[6] = run + aux[2] + aux[3] + aux[4] + aux[5];
        __syncthreads();
        if (aux[6] >= ties) break;
    }
    if (t == 0) *cut_out = aux[7];
    __syncthreads();
    return u_t;
}

// ---------------- Kernel A: zero scratch header + per-block max of x --------------
__global__ __launch_bounds__(256) void kA(const float4* __restrict__ x4,
                                          unsigned* __restrict__ ws) {
    if (blockIdx.x == 0)
        for (int i = threadIdx.x; i < 1024; i += 256) ws[i] = 0u;
    unsigned m = 0;
    const int nvec = BR * EC / 4;
    int stride = gridDim.x * 256;
    for (int v = blockIdx.x * 256 + threadIdx.x; v < nvec; v += stride) {
        float4 xv = x4[v];
        m = umax_(m, map_f(xv.x)); m = umax_(m, map_f(xv.y));
        m = umax_(m, map_f(xv.z)); m = umax_(m, map_f(xv.w));
    }
    for (int off = 32; off; off >>= 1) m = umax_(m, __shfl_down(m, off, 64));
    __shared__ unsigned sm[4];
    if ((threadIdx.x & 63) == 0) sm[threadIdx.x >> 6] = m;
    __syncthreads();
    if (threadIdx.x == 0)
        ws[WS_BMAX + blockIdx.x] = umax_(umax_(sm[0], sm[1]), umax_(sm[2], sm[3]));
}

// -------- Kernel B: gmax + sample-threshold + collect + npos + DEFAULT outputs ----
// 512 threads (8 waves): streaming phase wants full occupancy (32 waves/CU cap).
__global__ __launch_bounds__(BD) void kB(const float* __restrict__ x,
                                         const float* __restrict__ bt,
                                         const float* __restrict__ sp,
                                         const float* __restrict__ bp_p,
                                         unsigned* __restrict__ ws,
                                         nf4* __restrict__ out4,
                                         nf4* __restrict__ fb4) {
    __shared__ unsigned hist[BINS];               // 16KB
    __shared__ unsigned lu[LCAP], li[LCAP];       // 8KB
    __shared__ unsigned ssum[256], sabove[256];   // 2KB
    __shared__ unsigned sred[8];
    __shared__ unsigned stlo, slcnt, sgbase;
    int t = threadIdx.x;
    int row = blockIdx.x >> 4, chunk = blockIdx.x & (CHUNKS - 1);

    // 1) gmax from 1024 per-block maxima (redundant per block; L2-hot)
    unsigned m = 0;
    for (int i = t; i < 1024; i += BD) m = umax_(m, ws[WS_BMAX + i]);
    for (int off = 32; off; off >>= 1) m = umax_(m, __shfl_down(m, off, 64));
    if ((t & 63) == 0) sred[t >> 6] = m;
    __syncthreads();
    unsigned gmu = 0;
    #pragma unroll
    for (int w = 0; w < BD / 64; ++w) gmu = umax_(gmu, sred[w]);
    if (blockIdx.x == 0 && t == 0) ws[WS_GMAX] = gmu;
    float gmax = unmap_f(gmu);
    float bp = *bp_p;

    // 2) sample histogram (top-12 bits of u)
    for (int i = t; i < BINS; i += BD) hist[i] = 0;
    if (t == 0) slcnt = 0;
    __syncthreads();
    const float* xr = x + (size_t)row * EC;
    const float* br = bt + (size_t)row * EC;
    for (int s = t; s < NS; s += BD) {
        int idx = (s >> 6) * SSTRIDE + (s & 63);
        float nb, bo;
        compute_vals(xr[idx], br[idx], gmax, bp, &nb, &bo);
        atomicAdd(&hist[map_f(bo) >> 20], 1u);
    }
    __syncthreads();

    // 3) threshold = lower edge of bin holding rank-R sample (conservative)
    unsigned K = calc_K(sp);
    unsigned R = (unsigned)ceilf(1.75f * (float)NS * (float)K / (float)EC);
    if (R < 32) R = 32;
    if (R > NS) R = NS;
    if (t < 256) {
        unsigned hv[16];
        unsigned s = 0;
        #pragma unroll
        for (int j = 0; j < 16; ++j) { hv[j] = hist[t * 16 + j]; s += hv[j]; }
        ssum[t] = s;
        __syncthreads();
        if (t == 0) {
            unsigned acc = 0;
            for (int q = 255; q >= 0; --q) { sabove[q] = acc; acc += ssum[q]; }
        }
        __syncthreads();
        unsigned cum = sabove[t];
        for (int j = 15; j >= 0; --j) {
            unsigned h = hv[j];
            if (cum < R && cum + h >= R) stlo = ((unsigned)(t * 16 + j)) << 20;
            cum += h;
        }
    } else {
        __syncthreads();
        __syncthreads();
    }
    __syncthreads();
    unsigned tlo = stlo ? stlo - 1u : 0u;   // u > tlo  <=>  u >= bin lower edge

    // 4) collect candidates + npos + write default outputs
    const float4* x4 = (const float4*)x;
    const float4* bt4 = (const float4*)bt;
    unsigned* cu = ws + CAND_U_OFF + (size_t)row * CAP;
    unsigned* ci = ws + CAND_I_OFF + (size_t)row * CAP;
    size_t base = (size_t)row * (EC / 4) + (size_t)chunk * CHUNK_V;
    int ebase = chunk * (EC / CHUNKS);
    const nf4 zo = {0.0f, 0.0f, 0.0f, 0.0f};
    unsigned posc = 0;
    for (int v = t; v < CHUNK_V; v += BD) {
        float4 xv = x4[base + v];
        float4 bv = bt4[base + v];
        float xs[4] = {xv.x, xv.y, xv.z, xv.w};
        float bs[4] = {bv.x, bv.y, bv.z, bv.w};
        nf4 fv;
        #pragma unroll
        for (int j = 0; j < 4; ++j) {
            float nb, bo;
            compute_vals(xs[j], bs[j], gmax, bp, &nb, &bo);
            unsigned u = map_f(bo);
            fv[j] = nb;
            posc += (u > 0x80000000u) ? 1u : 0u;
            if (u > tlo) {
                unsigned p = atomicAdd(&slcnt, 1u);
                if (p < LCAP) {
                    lu[p] = u; li[p] = (unsigned)(ebase + v * 4 + j);
                } else {  // overflow fallback (rare)
                    unsigned gp = atomicAdd(&ws[WS_CCNT + row], 1u);
                    if (gp < CAP) { cu[gp] = u; ci[gp] = (unsigned)(ebase + v * 4 + j); }
                }
            }
        }
        __builtin_nontemporal_store(zo, &out4[base + v]);
        __builtin_nontemporal_store(fv, &fb4[base + v]);
    }
    for (int off = 32; off; off >>= 1) posc += __shfl_down(posc, off, 64);
    if ((t & 63) == 0) sred[t >> 6] = posc;
    __syncthreads();
    if (t == 0) {
        unsigned tot = 0;
        #pragma unroll
        for (int w = 0; w < BD / 64; ++w) tot += sred[w];
        atomicAdd(&ws[WS_NPOS + row], tot);
    }
    __syncthreads();
    unsigned n = slcnt < LCAP ? slcnt : LCAP;
    if (t == 0) sgbase = atomicAdd(&ws[WS_CCNT + row], n);
    __syncthreads();
    unsigned gb = sgbase;
    for (unsigned i = t; i < n; i += BD) {
        unsigned gp = gb + i;
        if (gp < CAP) { cu[gp] = lu[i]; ci[gp] = li[i]; }
    }
}

// -------- Kernel C: exact rank-K select + tie-cut + scatter-fix + gated correction
// active = sum_r min(K, npos[r])  [exact: selection picks exactly K; if npos>=K the
// K-th largest is positive -> saved=K; else all positives selected -> saved=npos]
__global__ __launch_bounds__(256) void kC(const float* __restrict__ x,
                                          const float* __restrict__ bt,
                                          const float* __restrict__ sp,
                                          const float* __restrict__ bp_p,
                                          unsigned* __restrict__ ws,
                                          float* __restrict__ out,
                                          float* __restrict__ fb) {
    int row = blockIdx.x;
    int t = threadIdx.x;
    unsigned n = ws[WS_CCNT + row];
    unsigned K = calc_K(sp);
    float gmax = unmap_f(ws[WS_GMAX]);
    float bp = *bp_p;
    const float* xr = x + (size_t)row * EC;
    const float* br = bt + (size_t)row * EC;
    float* outr = out + (size_t)row * EC;
    float* fbr = fb + (size_t)row * EC;
    __shared__ unsigned su[CAP];
    __shared__ unsigned hist[256], scan[256], sb[2];
    __shared__ unsigned marr[256];
    __shared__ unsigned mcnt;
    __shared__ unsigned aux[8];
    __shared__ unsigned sact, scut;
    if (n >= K && n <= CAP) {
        const unsigned* cu = ws + CAND_U_OFF + (size_t)row * CAP;
        const unsigned* ci = ws + CAND_I_OFF + (size_t)row * CAP;
        for (unsigned i = t; i < n; i += 256) su[i] = cu[i];
        if (t == 0) mcnt = 0;
        __syncthreads();
        unsigned krem2;
        unsigned u_t = lds_radix_select(su, n, K, hist, scan, sb, t, &krem2);
        for (unsigned i = t; i < n; i += 256)
            if (su[i] == u_t) {
                unsigned p = atomicAdd(&mcnt, 1u);
                if (p < 256) marr[p] = ci[i];
            }
        __syncthreads();
        unsigned m = mcnt;
        if (m <= 256) {
            for (unsigned i = t; i < m; i += 256) {
                unsigned myidx = marr[i];
                unsigned r = 0;
                for (unsigned j = 0; j < m; ++j) r += (marr[j] < myidx) ? 1u : 0u;
                if (r == krem2 - 1) scut = myidx;
            }
        } else {  // pathological tie overflow: correct slow path
            for (unsigned i = t; i < n; i += 256) {
                if (su[i] == u_t) {
                    unsigned myidx = ci[i];
                    unsigned r = 0;
                    for (unsigned j = 0; j < n; ++j)
                        if (su[j] == u_t && ci[j] < myidx) ++r;
                    if (r == krem2 - 1) scut = myidx;
                }
            }
        }
        __syncthreads();
        unsigned cut = scut;
        // scatter-fix selected entries (defaults already written by kB)
        for (unsigned i = t; i < n; i += 256) {
            unsigned u = su[i], idx = ci[i];
            bool sel = (u > u_t) || ((u == u_t) && (idx <= cut));
            if (sel && u > 0x80000000u) { outr[idx] = 1.0f; fbr[idx] = 0.0f; }
        }
    } else {
        // estimate failed (never for this data): exact full-row select + full fix
        unsigned u_t = row_select_full<0>(xr, br, gmax, bp, K, hist, aux, t, &scut);
        unsigned cut = scut;
        for (int i = t; i < EC; i += 256) {
            float nb, bo;
            compute_vals(xr[i], br[i], gmax, bp, &nb, &bo);
            unsigned u = map_f(bo);
            bool sel = (u > u_t) || ((u == u_t) && ((unsigned)i <= cut));
            if (sel && u > 0x80000000u) { outr[i] = 1.0f; fbr[i] = 0.0f; }
        }
    }

    // ---- global active + gated correction branch (dead for this input) ----
    unsigned act = 0;
    if (t < 64) act = umin_(K, ws[WS_NPOS + t]);
    for (int off = 32; off; off >>= 1) act += __shfl_down(act, off, 64);
    if (t == 0) sact = act;
    __syncthreads();
    float active = (float)sact;
    float min_active = floorf(sp[0] * (float)EC);
    if (active < min_active) {
        unsigned K2 = (unsigned)ceilf(min_active - active);
        if (K2 > EC) K2 = EC;
        unsigned ut2 = row_select_full<1>(xr, br, gmax, bp, K2, hist, aux, t, &scut);
        unsigned cut2 = scut;
        for (int i = t; i < EC; i += 256) {
            float nb, bo;
            compute_vals(xr[i], br[i], gmax, bp, &nb, &bo);
            unsigned u2 = map_f(nb);
            if (u2 > ut2 || (u2 == ut2 && (unsigned)i <= cut2)) {
                outr[i] = 1.0f;
                fbr[i] = 0.0f;
            }
        }
    }
}

extern "C" void kernel_launch(void* const* d_in, const int* in_sizes, int n_in,
                              void* d_out, int out_size, void* d_ws, size_t ws_size,
                              hipStream_t stream) {
    const float* x  = (const float*)d_in[0];
    const float* bt = (const float*)d_in[1];
    const float* sp = (const float*)d_in[2];
    const float* bp = (const float*)d_in[3];
    float* out = (float*)d_out;
    float* fb  = out + (size_t)BR * EC;
    unsigned* ws = (unsigned*)d_ws;

    kA<<<1024, 256, 0, stream>>>((const float4*)x, ws);
    kB<<<BR * CHUNKS, BD, 0, stream>>>(x, bt, sp, bp, ws, (nf4*)out, (nf4*)fb);
    kC<<<BR, 256, 0, stream>>>(x, bt, sp, bp, ws, out, fb);
}